// Round 15
// baseline (1061.637 us; speedup 1.0000x reference)
//
#include <hip/hip_runtime.h>

#define NNODE 100000
#define NCLS  50000
#define NEDGE 400000
#define NDIM  43
#define CDIM  2
#define HID   128
#define NHEAD 4
#define CHN   32
#define NLAY  4

typedef unsigned short u16;
typedef unsigned int u32;
typedef __attribute__((ext_vector_type(8))) short bf16x8;
typedef __attribute__((ext_vector_type(4))) float f32x4;

// fp32 -> bf16 round-to-nearest-even
__device__ __forceinline__ u16 f2bf(float f) {
  u32 u = __float_as_uint(f);
  return (u16)((u + 0x7FFFu + ((u >> 16) & 1u)) >> 16);
}
__device__ __forceinline__ float bf2f(u16 h) {
  return __uint_as_float(((u32)h) << 16);
}

// ---------------------------------------------------------------------------
// Class projection (K=2): writes hi/lo bf16 state arrays.
__global__ void proj_kernel(const float* __restrict__ X, const float* __restrict__ W,
                            const float* __restrict__ B, u16* __restrict__ Yh,
                            u16* __restrict__ Yl, int nrows, int K) {
  int t = blockIdx.x * blockDim.x + threadIdx.x;
  if (t >= nrows * HID) return;
  int i = t >> 7, j = t & (HID - 1);
  float acc = B[j];
  for (int k = 0; k < K; ++k)
    acc = fmaf(X[i * K + k], W[k * HID + j], acc);
  u16 h = f2bf(acc);
  Yh[t] = h;
  Yl[t] = f2bf(acc - bf2f(h));
}

// ---------------------------------------------------------------------------
// Node projection, K=43, LDS-tiled. Writes hi/lo bf16 state arrays.
__global__ __launch_bounds__(256) void proj_node(const float* __restrict__ X,
                                                 const float* __restrict__ W,
                                                 const float* __restrict__ B,
                                                 u16* __restrict__ Yh,
                                                 u16* __restrict__ Yl) {
  __shared__ float Ws[NDIM][HID];   // 22016 B, [k][j]
  __shared__ float Xs[32][NDIM];    // 5504 B,  [r][k]
  const int tid = threadIdx.x;
  const int row0 = blockIdx.x * 32;

  for (int i = tid; i < NDIM * (HID / 4); i += 256) {
    int k = i >> 5, j4 = (i & 31) << 2;
    *(float4*)&Ws[k][j4] = *(const float4*)&W[(size_t)k * HID + j4];
  }
  const float* Xb = X + (size_t)row0 * NDIM;
  for (int i = tid; i < 32 * NDIM; i += 256) ((float*)Xs)[i] = Xb[i];
  __syncthreads();

  const int cg = tid & 31, rg = tid >> 5;
  const int j0 = cg * 4, r0 = rg * 4;

  float acc[4][4];
#pragma unroll
  for (int rr = 0; rr < 4; ++rr)
#pragma unroll
    for (int cc = 0; cc < 4; ++cc) acc[rr][cc] = 0.f;

#pragma unroll 4
  for (int k = 0; k < NDIM; ++k) {
    const float4 w = *(const float4*)&Ws[k][j0];
    const float wv[4] = {w.x, w.y, w.z, w.w};
    const float xx[4] = {Xs[r0 + 0][k], Xs[r0 + 1][k], Xs[r0 + 2][k], Xs[r0 + 3][k]};
#pragma unroll
    for (int rr = 0; rr < 4; ++rr)
#pragma unroll
      for (int cc = 0; cc < 4; ++cc)
        acc[rr][cc] = fmaf(xx[rr], wv[cc], acc[rr][cc]);
  }

  const float4 bv = *(const float4*)&B[j0];
  const float bb[4] = {bv.x, bv.y, bv.z, bv.w};
#pragma unroll
  for (int rr = 0; rr < 4; ++rr) {
    int gr = row0 + r0 + rr;
    ushort4 ho, lo_;
    float v0 = acc[rr][0] + bb[0], v1 = acc[rr][1] + bb[1];
    float v2 = acc[rr][2] + bb[2], v3 = acc[rr][3] + bb[3];
    ho.x = f2bf(v0); lo_.x = f2bf(v0 - bf2f(ho.x));
    ho.y = f2bf(v1); lo_.y = f2bf(v1 - bf2f(ho.y));
    ho.z = f2bf(v2); lo_.z = f2bf(v2 - bf2f(ho.z));
    ho.w = f2bf(v3); lo_.w = f2bf(v3 - bf2f(ho.w));
    *(ushort4*)&Yh[(size_t)gr * HID + j0] = ho;
    *(ushort4*)&Yl[(size_t)gr * HID + j0] = lo_;
  }
}

// ---------------------------------------------------------------------------
// Weight prep: W [128][128] fp32 -> MFMA B-fragment-ordered bf16 hi/lo.
__global__ __launch_bounds__(256) void wprep(const float* __restrict__ n2c_wl,
                                             const float* __restrict__ n2c_wr,
                                             const float* __restrict__ c2n_wl,
                                             const float* __restrict__ c2n_wr,
                                             u16* __restrict__ wp) {
  int gid = blockIdx.x * 256 + threadIdx.x;  // 32768 total
  int lane = gid & 63;
  int t = gid >> 6;                          // 512: m(16) x ks(4) x ct(8)
  int ct = t & 7, ks = (t >> 3) & 3, m = t >> 5;
  const float* Wb;
  switch (m >> 2) {
    case 0: Wb = n2c_wl; break;
    case 1: Wb = n2c_wr; break;
    case 2: Wb = c2n_wl; break;
    default: Wb = c2n_wr; break;
  }
  Wb += (size_t)(m & 3) * HID * HID;
  const int kg = lane >> 4, c = ct * 16 + (lane & 15);
  u16 hi[8], lo[8];
#pragma unroll
  for (int e = 0; e < 8; ++e) {
    float v = Wb[(size_t)(ks * 32 + kg * 8 + e) * HID + c];
    hi[e] = f2bf(v);
    lo[e] = f2bf(v - bf2f(hi[e]));
  }
  size_t base = (size_t)m * 32768 + ((size_t)(ks * 8 + ct) * 64 + lane) * 8;
#pragma unroll
  for (int e = 0; e < 8; ++e) {
    wp[base + e] = hi[e];
    wp[base + 16384 + e] = lo[e];
  }
}

// ---------------------------------------------------------------------------
// MFMA-GEMM frame v2: 32 rows per wave (two 16-row sets), block = 128 rows.
// Each wave reads the 64KB packed W once but feeds 6 MFMAs per Bh/Bl pair
// (2x the arithmetic intensity of the 16-row version -> hides B-load latency).
// `blk` must be defined before invoking (block index within this matrix).
#define GEMM_FRAME                                                     \
  const int tid = threadIdx.x;                                         \
  const int lane = tid & 63;                                           \
  const int wv = tid >> 6;                                             \
  const int row0 = blk * 128 + wv * 32;                                \
  const int ri = lane & 15;                                            \
  const int kg = lane >> 4;                                            \
  bf16x8 Ah[2][4], Al[2][4];                                           \
  _Pragma("unroll") for (int s = 0; s < 2; ++s) {                      \
    int r = row0 + s * 16 + ri;                                        \
    r = r < nrows ? r : nrows - 1;                                     \
    const size_t xbase = (size_t)r * HID + kg * 8;                     \
    _Pragma("unroll") for (int ks = 0; ks < 4; ++ks) {                 \
      Ah[s][ks] = *(const bf16x8*)&Xh[xbase + ks * 32];                \
      Al[s][ks] = *(const bf16x8*)&Xl[xbase + ks * 32];                \
    }                                                                  \
  }

#define GEMM_CORE                                                                           \
  f32x4 acc[2][8];                                                                          \
  _Pragma("unroll") for (int s = 0; s < 2; ++s)                                             \
    _Pragma("unroll") for (int ct = 0; ct < 8; ++ct)                                        \
      acc[s][ct] = (f32x4){0.f, 0.f, 0.f, 0.f};                                             \
  _Pragma("unroll") for (int ks = 0; ks < 4; ++ks) {                                        \
    const u16* wb = wp + ((size_t)(ks * 8) * 64 + lane) * 8;                                \
    _Pragma("unroll") for (int ct = 0; ct < 8; ++ct) {                                      \
      bf16x8 Bh = *(const bf16x8*)&wb[ct * 512];                                            \
      bf16x8 Bl = *(const bf16x8*)&wb[16384 + ct * 512];                                    \
      _Pragma("unroll") for (int s = 0; s < 2; ++s) {                                       \
        acc[s][ct] = __builtin_amdgcn_mfma_f32_16x16x32_bf16(Ah[s][ks], Bh, acc[s][ct], 0, 0, 0); \
        acc[s][ct] = __builtin_amdgcn_mfma_f32_16x16x32_bf16(Al[s][ks], Bh, acc[s][ct], 0, 0, 0); \
        acc[s][ct] = __builtin_amdgcn_mfma_f32_16x16x32_bf16(Ah[s][ks], Bl, acc[s][ct], 0, 0, 0); \
      }                                                                                     \
    }                                                                                       \
  }

#define GEMM_STORE                                                     \
  _Pragma("unroll") for (int s = 0; s < 2; ++s) {                      \
    _Pragma("unroll") for (int ct = 0; ct < 8; ++ct) {                 \
      const float bias = B[ct * 16 + ri];                              \
      _Pragma("unroll") for (int i = 0; i < 4; ++i) {                  \
        int gr = row0 + s * 16 + kg * 4 + i;                           \
        if (gr < nrows) Y[(size_t)gr * HID + ct * 16 + ri] =           \
            f2bf(acc[s][ct][i] + bias);                                \
      }                                                                \
    }                                                                  \
  }

// Single GEMM, bf16 output.
__global__ __launch_bounds__(256) void gemm_mfma_h(const u16* __restrict__ Xh,
                                                   const u16* __restrict__ Xl,
                                                   const u16* __restrict__ wp,
                                                   const float* __restrict__ B,
                                                   u16* __restrict__ Y, int nrows) {
  const int blk = blockIdx.x;
  GEMM_FRAME
  GEMM_CORE
  GEMM_STORE
}

// Dual-GEMM in one launch via grid partition: blocks [0,gbase) compute
// YA = X@WA+BA, blocks [gbase,2*gbase) compute YB = X@WB+BB.
__global__ __launch_bounds__(256) void gemm_mfma_h2(const u16* __restrict__ Xh,
                                                    const u16* __restrict__ Xl,
                                                    const u16* __restrict__ wpA,
                                                    const float* __restrict__ BA,
                                                    u16* __restrict__ YA,
                                                    const u16* __restrict__ wpB,
                                                    const float* __restrict__ BB,
                                                    u16* __restrict__ YB,
                                                    int nrows, int gbase) {
  const bool second = (int)blockIdx.x >= gbase;
  const u16* wp = second ? wpB : wpA;
  const float* B = second ? BB : BA;
  u16* Y = second ? YB : YA;
  const int blk = second ? blockIdx.x - gbase : blockIdx.x;
  GEMM_FRAME
  GEMM_CORE
  GEMM_STORE
}

// ---------------------------------------------------------------------------
// CSR build (both graphs per launch): histogram -> scan -> scatter
__global__ void hist2(const int* __restrict__ mdst, const int* __restrict__ cdst,
                      int* __restrict__ cnt_c, int* __restrict__ cnt_n) {
  int e = blockIdx.x * 256 + threadIdx.x;
  if (e < NEDGE) atomicAdd(&cnt_c[mdst[e]], 1);
  else {
    e -= NEDGE;
    if (e < NEDGE) atomicAdd(&cnt_n[cdst[e]], 1);
  }
}

// block bb covers 1024 elements (4/thread); pre[i] = exclusive prefix in block
__global__ __launch_bounds__(256) void scan2(const int* __restrict__ cnt_c,
                                             int* __restrict__ pre_c,
                                             int* __restrict__ bsum_c,
                                             const int* __restrict__ cnt_n,
                                             int* __restrict__ pre_n,
                                             int* __restrict__ bsum_n, int nbC) {
  __shared__ int sdata[256];
  const int b = blockIdx.x, t = threadIdx.x;
  const int* cnt; int* pre; int* bsum; int n; int bb;
  if (b < nbC) { cnt = cnt_c; pre = pre_c; bsum = bsum_c; n = NCLS; bb = b; }
  else { cnt = cnt_n; pre = pre_n; bsum = bsum_n; n = NNODE; bb = b - nbC; }
  const int base = bb * 1024 + t * 4;
  int v[4], s = 0;
#pragma unroll
  for (int q = 0; q < 4; ++q) {
    int i = base + q;
    v[q] = (i < n) ? cnt[i] : 0;
    s += v[q];
  }
  sdata[t] = s;
  __syncthreads();
  for (int off = 1; off < 256; off <<= 1) {
    int y = (t >= off) ? sdata[t - off] : 0;
    __syncthreads();
    sdata[t] += y;
    __syncthreads();
  }
  int run = sdata[t] - s;
  if (t == 255) bsum[bb] = sdata[255];
#pragma unroll
  for (int q = 0; q < 4; ++q) {
    int i = base + q;
    if (i < n) pre[i] = run;
    run += v[q];
  }
}

// 2 blocks: block 0 scans bsum_c (nbC), block 1 bsum_n (nbN); nb <= 128
__global__ __launch_bounds__(128) void scanp2(int* __restrict__ bsum_c, int nbC,
                                              int* __restrict__ bsum_n, int nbN) {
  __shared__ int sd[128];
  int* bs = blockIdx.x ? bsum_n : bsum_c;
  int nb = blockIdx.x ? nbN : nbC;
  int t = threadIdx.x;
  int v = (t < nb) ? bs[t] : 0;
  sd[t] = v;
  __syncthreads();
  for (int off = 1; off < 128; off <<= 1) {
    int y = (t >= off) ? sd[t - off] : 0;
    __syncthreads();
    sd[t] += y;
    __syncthreads();
  }
  if (t < nb) bs[t] = sd[t] - v;  // exclusive
}

__global__ void fin2(const int* __restrict__ pre_c, const int* __restrict__ bsum_c,
                     int* __restrict__ rowptr_c,
                     const int* __restrict__ pre_n, const int* __restrict__ bsum_n,
                     int* __restrict__ rowptr_n) {
  int i = blockIdx.x * 256 + threadIdx.x;
  if (i < NCLS) {
    rowptr_c[i] = pre_c[i] + bsum_c[i >> 10];
    if (i == 0) { rowptr_c[NCLS] = NEDGE; rowptr_n[NNODE] = NEDGE; }
  } else {
    int t = i - NCLS;
    if (t < NNODE) rowptr_n[t] = pre_n[t] + bsum_n[t >> 10];
  }
}

__global__ void scatter2(const int* __restrict__ msrc, const int* __restrict__ mdst,
                         const int* __restrict__ rowptr_c, int* __restrict__ cur_c,
                         int* __restrict__ csr_c,
                         const int* __restrict__ csrc, const int* __restrict__ cdst,
                         const int* __restrict__ rowptr_n, int* __restrict__ cur_n,
                         int* __restrict__ csr_n) {
  int e = blockIdx.x * 256 + threadIdx.x;
  if (e < NEDGE) {
    int d = mdst[e];
    int p = atomicAdd(&cur_c[d], 1);
    csr_c[rowptr_c[d] + p] = msrc[e];
  } else {
    e -= NEDGE;
    if (e < NEDGE) {
      int d = cdst[e];
      int p = atomicAdd(&cur_n[d], 1);
      csr_n[rowptr_n[d] + p] = csrc[e];
    }
  }
}

// ---------------------------------------------------------------------------
// Fused per-dst GATv2: TWO rows per wave, 4-deep edge unroll
// (8 edge-gathers in flight per wave). Lanes 0-31 -> row 2t, 32-63 -> 2t+1;
// 4 channels/lane. Degree mismatch branchless (invalid edges e_=0).
__global__ __launch_bounds__(256) void gat_dst(u16* __restrict__ xh,
                                               u16* __restrict__ xlo,
                                               const u16* __restrict__ flh,    // [n_src][128] bf16
                                               const u16* __restrict__ frh,    // [n_dst][128] bf16
                                               const int* __restrict__ rowptr,
                                               const int* __restrict__ csr_src,
                                               const float* __restrict__ att,  // [128]
                                               const float* __restrict__ bias,
                                               const float* __restrict__ g,
                                               const float* __restrict__ b,
                                               int n_dst) {
  const int wave = threadIdx.x >> 6;     // 0..3
  const int lane = threadIdx.x & 63;
  const int half = lane >> 5;            // row within pair
  const int sub = lane & 31;
  const int j0 = sub * 4;                // channels j0..j0+3; head = sub>>3

  const float4 attv = *(const float4*)&att[j0];
  const float4 bias4 = *(const float4*)&bias[j0];
  const float4 g4 = *(const float4*)&g[j0];
  const float4 b4 = *(const float4*)&b[j0];

  const int npairs = n_dst >> 1;
  const int stride = gridDim.x * 4;
  for (int t = blockIdx.x * 4 + wave; t < npairs; t += stride) {
    const int d = 2 * t + half;
    const ushort4 rr = *(const ushort4*)&frh[(size_t)d * HID + j0];
    const float xr0 = bf2f(rr.x), xr1 = bf2f(rr.y), xr2 = bf2f(rr.z), xr3 = bf2f(rr.w);
    const int e0 = rowptr[d], e1 = rowptr[d + 1];
    const int deg = e1 - e0;
    const int dego = __shfl_xor(deg, 32);
    const int kmax = deg > dego ? deg : dego;

    float a0 = 0.f, a1 = 0.f, a2 = 0.f, a3 = 0.f, den = 0.f;

#define GAT_EDGE(wv, ok)                                              \
    {                                                                 \
      float c0 = bf2f(wv.x), c1 = bf2f(wv.y);                         \
      float c2 = bf2f(wv.z), c3 = bf2f(wv.w);                         \
      float m0 = c0 + xr0; m0 = m0 > 0.f ? m0 : 0.2f * m0;            \
      float m1 = c1 + xr1; m1 = m1 > 0.f ? m1 : 0.2f * m1;            \
      float m2 = c2 + xr2; m2 = m2 > 0.f ? m2 : 0.2f * m2;            \
      float m3 = c3 + xr3; m3 = m3 > 0.f ? m3 : 0.2f * m3;            \
      float p = fmaf(attv.x, m0, fmaf(attv.y, m1,                      \
                fmaf(attv.z, m2, attv.w * m3)));                      \
      p += __shfl_xor(p, 1);                                          \
      p += __shfl_xor(p, 2);                                          \
      p += __shfl_xor(p, 4);                                          \
      float e_ = (ok) ? __expf(p) : 0.f;                              \
      a0 = fmaf(e_, c0, a0); a1 = fmaf(e_, c1, a1);                   \
      a2 = fmaf(e_, c2, a2); a3 = fmaf(e_, c3, a3);                   \
      den += e_;                                                      \
    }

    int k = 0;
    for (; k + 3 < kmax; k += 4) {
      int idx = e0 + k;
      bool ok0 = idx < e1, ok1 = idx + 1 < e1, ok2 = idx + 2 < e1, ok3 = idx + 3 < e1;
      int i0 = min(idx, NEDGE - 1), i1 = min(idx + 1, NEDGE - 1);
      int i2 = min(idx + 2, NEDGE - 1), i3 = min(idx + 3, NEDGE - 1);
      int s0 = csr_src[i0], s1 = csr_src[i1], s2 = csr_src[i2], s3 = csr_src[i3];
      ushort4 w0 = *(const ushort4*)&flh[(size_t)s0 * HID + j0];
      ushort4 w1 = *(const ushort4*)&flh[(size_t)s1 * HID + j0];
      ushort4 w2 = *(const ushort4*)&flh[(size_t)s2 * HID + j0];
      ushort4 w3 = *(const ushort4*)&flh[(size_t)s3 * HID + j0];
      GAT_EDGE(w0, ok0)
      GAT_EDGE(w1, ok1)
      GAT_EDGE(w2, ok2)
      GAT_EDGE(w3, ok3)
    }
    for (; k < kmax; ++k) {
      int idx = e0 + k;
      bool ok0 = idx < e1;
      int i0 = min(idx, NEDGE - 1);
      int s0 = csr_src[i0];
      ushort4 w0 = *(const ushort4*)&flh[(size_t)s0 * HID + j0];
      GAT_EDGE(w0, ok0)
    }
#undef GAT_EDGE

    float rden = (e1 > e0) ? 1.0f / den : 0.f;
    float o0 = a0 * rden, o1 = a1 * rden, o2 = a2 * rden, o3 = a3 * rden;

    // residual from hi/lo state
    const ushort4 hh = *(const ushort4*)&xh[(size_t)d * HID + j0];
    const ushort4 ll = *(const ushort4*)&xlo[(size_t)d * HID + j0];
    float v0 = bf2f(hh.x) + bf2f(ll.x) + o0 + bias4.x;
    float v1 = bf2f(hh.y) + bf2f(ll.y) + o1 + bias4.y;
    float v2 = bf2f(hh.z) + bf2f(ll.z) + o2 + bias4.z;
    float v3 = bf2f(hh.w) + bf2f(ll.w) + o3 + bias4.w;

    // LayerNorm within the 32-lane half (32 lanes x 4 channels = 128)
    float s1 = v0 + v1 + v2 + v3;
    float s2 = v0 * v0 + v1 * v1 + v2 * v2 + v3 * v3;
#pragma unroll
    for (int off = 16; off > 0; off >>= 1) {
      s1 += __shfl_xor(s1, off);
      s2 += __shfl_xor(s2, off);
    }
    const float mu = s1 * (1.0f / HID);
    const float var = s2 * (1.0f / HID) - mu * mu;
    const float inv = rsqrtf(var + 1e-5f);
    float o0n = (v0 - mu) * inv * g4.x + b4.x;
    float o1n = (v1 - mu) * inv * g4.y + b4.y;
    float o2n = (v2 - mu) * inv * g4.z + b4.z;
    float o3n = (v3 - mu) * inv * g4.w + b4.w;

    ushort4 ho, lo_;
    ho.x = f2bf(o0n); lo_.x = f2bf(o0n - bf2f(ho.x));
    ho.y = f2bf(o1n); lo_.y = f2bf(o1n - bf2f(ho.y));
    ho.z = f2bf(o2n); lo_.z = f2bf(o2n - bf2f(ho.z));
    ho.w = f2bf(o3n); lo_.w = f2bf(o3n - bf2f(ho.w));
    *(ushort4*)&xh[(size_t)d * HID + j0] = ho;
    *(ushort4*)&xlo[(size_t)d * HID + j0] = lo_;
  }
}

// ---------------------------------------------------------------------------
__global__ void colsum(const u16* __restrict__ xh, const u16* __restrict__ xlo,
                       float* __restrict__ acc) {
  int j = threadIdx.x;  // 128 threads
  int per = (NCLS + gridDim.x - 1) / gridDim.x;
  int r0 = blockIdx.x * per;
  int r1 = min(r0 + per, NCLS);
  float s = 0.f;
  for (int r = r0; r < r1; ++r)
    s += bf2f(xh[(size_t)r * HID + j]) + bf2f(xlo[(size_t)r * HID + j]);
  atomicAdd(&acc[j], s);
}

__global__ void final_out(const float* __restrict__ acc, float* __restrict__ out) {
  int j = threadIdx.x;
  out[j] = acc[j] * (1.0f / NCLS);
}

// ---------------------------------------------------------------------------
extern "C" void kernel_launch(void* const* d_in, const int* in_sizes, int n_in,
                              void* d_out, int out_size, void* d_ws, size_t ws_size,
                              hipStream_t stream) {
  (void)in_sizes; (void)n_in; (void)out_size; (void)ws_size;
  const float* x_node     = (const float*)d_in[0];
  const float* x_class    = (const float*)d_in[1];
  const int* member_src   = (const int*)d_in[2];
  const int* member_dst   = (const int*)d_in[3];
  const int* contains_src = (const int*)d_in[4];
  const int* contains_dst = (const int*)d_in[5];
  const float* npw = (const float*)d_in[6];
  const float* npb = (const float*)d_in[7];
  const float* cpw = (const float*)d_in[8];
  const float* cpb = (const float*)d_in[9];
  const float* n2c_wl   = (const float*)d_in[10];
  const float* n2c_bl   = (const float*)d_in[11];
  const float* n2c_wr   = (const float*)d_in[12];
  const float* n2c_br   = (const float*)d_in[13];
  const float* n2c_att  = (const float*)d_in[14];
  const float* n2c_bias = (const float*)d_in[15];
  const float* c2n_wl   = (const float*)d_in[16];
  const float* c2n_bl   = (const float*)d_in[17];
  const float* c2n_wr   = (const float*)d_in[18];
  const float* c2n_br   = (const float*)d_in[19];
  const float* c2n_att  = (const float*)d_in[20];
  const float* c2n_bias = (const float*)d_in[21];
  const float* ln_cg = (const float*)d_in[22];
  const float* ln_cb = (const float*)d_in[23];
  const float* ln_ng = (const float*)d_in[24];
  const float* ln_nb = (const float*)d_in[25];

  // workspace layout
  u16* xnh = (u16*)d_ws;                             // NNODE*128 u16
  u16* xnl = xnh + (size_t)NNODE * HID;              // NNODE*128
  u16* xch = xnl + (size_t)NNODE * HID;              // NCLS*128
  u16* xcl = xch + (size_t)NCLS * HID;               // NCLS*128
  u16* flb = xcl + (size_t)NCLS * HID;               // NNODE*128 bf16
  u16* frn = flb + (size_t)NNODE * HID;              // NNODE*128 bf16
  u16* frc = frn + (size_t)NNODE * HID;              // NCLS*128 bf16
  float* accb = (float*)(frc + (size_t)NCLS * HID);  // 128
  int* rowptr_c = (int*)(accb + 128);                // NCLS+1
  int* csr_c    = rowptr_c + (NCLS + 1);             // NEDGE
  int* rowptr_n = csr_c + NEDGE;                     // NNODE+1
  int* csr_n    = rowptr_n + (NNODE + 1);            // NEDGE
  int* cnt_c    = csr_n + NEDGE;                     // NCLS (cnt_c..cur_n contiguous, 1 memset)
  int* cur_c    = cnt_c + NCLS;                      // NCLS
  int* cnt_n    = cur_c + NCLS;                      // NNODE
  int* cur_n    = cnt_n + NNODE;                     // NNODE
  int* pre_c    = cur_n + NNODE;                     // NCLS
  int* pre_n    = pre_c + NCLS;                      // NNODE
  int* bsum_c   = pre_n + NNODE;                     // 128
  int* bsum_n   = bsum_c + 128;                      // 128
  // packed weights overlay cnt/cursor region after CSR build (1 MB <= 1.2 MB)
  u16* wp = (u16*)cnt_c;

  const int nbC = (NCLS + 1023) / 1024;   // 49
  const int nbN = (NNODE + 1023) / 1024;  // 98
  const int EB2 = (2 * NEDGE + 255) / 256;
  const int GAT_BLOCKS = 2048;  // persistent: 2048 blocks x 4 waves, 2 rows/wave
  const int GB_N = (NNODE + 127) / 128;   // 128 rows/block now
  const int GB_C = (NCLS + 127) / 128;

  // ---- initial projections (write hi/lo state) ----
  proj_node<<<NNODE / 32, 256, 0, stream>>>(x_node, npw, npb, xnh, xnl);
  proj_kernel<<<(NCLS * HID + 255) / 256, 256, 0, stream>>>(x_class, cpw, cpb, xch, xcl, NCLS, CDIM);

  // ---- CSR build (both graphs per launch) ----
  hipMemsetAsync(cnt_c, 0, (size_t)(2 * NCLS + 2 * NNODE) * sizeof(int), stream);
  hist2<<<EB2, 256, 0, stream>>>(member_dst, contains_dst, cnt_c, cnt_n);
  scan2<<<nbC + nbN, 256, 0, stream>>>(cnt_c, pre_c, bsum_c, cnt_n, pre_n, bsum_n, nbC);
  scanp2<<<2, 128, 0, stream>>>(bsum_c, nbC, bsum_n, nbN);
  fin2<<<(NCLS + NNODE + 255) / 256, 256, 0, stream>>>(pre_c, bsum_c, rowptr_c,
                                                       pre_n, bsum_n, rowptr_n);
  scatter2<<<EB2, 256, 0, stream>>>(member_src, member_dst, rowptr_c, cur_c, csr_c,
                                    contains_src, contains_dst, rowptr_n, cur_n, csr_n);

  // ---- pack weights (cnt/cursor region dead now) ----
  wprep<<<128, 256, 0, stream>>>(n2c_wl, n2c_wr, c2n_wl, c2n_wr, wp);

  // prologue: frc = xc @ n2c_wr[0] + br[0]
  gemm_mfma_h<<<GB_C, 256, 0, stream>>>(xch, xcl, wp + (size_t)4 * 32768,
                                        n2c_br, frc, NCLS);

  // ---- layers ----
  for (int l = 0; l < NLAY; ++l) {
    // node-side dual launch: flb = xn @ n2c_wl[l]; frn = xn @ c2n_wr[l]
    gemm_mfma_h2<<<2 * GB_N, 256, 0, stream>>>(xnh, xnl,
                                               wp + (size_t)(0 + l) * 32768, n2c_bl + l * HID, flb,
                                               wp + (size_t)(12 + l) * 32768, c2n_br + l * HID, frn,
                                               NNODE, GB_N);
    // n2c gat: dst=class
    gat_dst<<<GAT_BLOCKS, 256, 0, stream>>>(xch, xcl, flb, frc, rowptr_c, csr_c,
                                            n2c_att + l * HID, n2c_bias + l * HID,
                                            ln_cg + l * HID, ln_cb + l * HID, NCLS);
    // class-side: flb = xc @ c2n_wl[l]; frc = xc @ n2c_wr[l+1] (when it exists)
    if (l < NLAY - 1) {
      gemm_mfma_h2<<<2 * GB_C, 256, 0, stream>>>(xch, xcl,
                                                 wp + (size_t)(8 + l) * 32768, c2n_bl + l * HID, flb,
                                                 wp + (size_t)(4 + l + 1) * 32768, n2c_br + (l + 1) * HID, frc,
                                                 NCLS, GB_C);
    } else {
      gemm_mfma_h<<<GB_C, 256, 0, stream>>>(xch, xcl, wp + (size_t)(8 + l) * 32768,
                                            c2n_bl + l * HID, flb, NCLS);
    }
    // c2n gat: dst=node
    gat_dst<<<GAT_BLOCKS, 256, 0, stream>>>(xnh, xnl, flb, frn, rowptr_n, csr_n,
                                            c2n_att + l * HID, c2n_bias + l * HID,
                                            ln_ng + l * HID, ln_nb + l * HID, NNODE);
  }

  hipMemsetAsync(accb, 0, HID * sizeof(float), stream);
  colsum<<<256, HID, 0, stream>>>(xch, xcl, accb);
  final_out<<<1, HID, 0, stream>>>(accb, (float*)d_out);
}

// Round 17
// 939.559 us; speedup vs baseline: 1.1299x; 1.1299x over previous
//
#include <hip/hip_runtime.h>

#define NNODE 100000
#define NCLS  50000
#define NEDGE 400000
#define NDIM  43
#define CDIM  2
#define HID   128
#define NHEAD 4
#define CHN   32
#define NLAY  4

typedef unsigned short u16;
typedef unsigned int u32;
typedef __attribute__((ext_vector_type(8))) short bf16x8;
typedef __attribute__((ext_vector_type(4))) float f32x4;

// fp32 -> bf16 round-to-nearest-even
__device__ __forceinline__ u16 f2bf(float f) {
  u32 u = __float_as_uint(f);
  return (u16)((u + 0x7FFFu + ((u >> 16) & 1u)) >> 16);
}
__device__ __forceinline__ float bf2f(u16 h) {
  return __uint_as_float(((u32)h) << 16);
}

// ---------------------------------------------------------------------------
// Class projection (K=2): writes hi/lo bf16 state arrays.
__global__ void proj_kernel(const float* __restrict__ X, const float* __restrict__ W,
                            const float* __restrict__ B, u16* __restrict__ Yh,
                            u16* __restrict__ Yl, int nrows, int K) {
  int t = blockIdx.x * blockDim.x + threadIdx.x;
  if (t >= nrows * HID) return;
  int i = t >> 7, j = t & (HID - 1);
  float acc = B[j];
  for (int k = 0; k < K; ++k)
    acc = fmaf(X[i * K + k], W[k * HID + j], acc);
  u16 h = f2bf(acc);
  Yh[t] = h;
  Yl[t] = f2bf(acc - bf2f(h));
}

// ---------------------------------------------------------------------------
// Node projection, K=43, LDS-tiled. Writes hi/lo bf16 state arrays.
__global__ __launch_bounds__(256) void proj_node(const float* __restrict__ X,
                                                 const float* __restrict__ W,
                                                 const float* __restrict__ B,
                                                 u16* __restrict__ Yh,
                                                 u16* __restrict__ Yl) {
  __shared__ float Ws[NDIM][HID];   // 22016 B, [k][j]
  __shared__ float Xs[32][NDIM];    // 5504 B,  [r][k]
  const int tid = threadIdx.x;
  const int row0 = blockIdx.x * 32;

  for (int i = tid; i < NDIM * (HID / 4); i += 256) {
    int k = i >> 5, j4 = (i & 31) << 2;
    *(float4*)&Ws[k][j4] = *(const float4*)&W[(size_t)k * HID + j4];
  }
  const float* Xb = X + (size_t)row0 * NDIM;
  for (int i = tid; i < 32 * NDIM; i += 256) ((float*)Xs)[i] = Xb[i];
  __syncthreads();

  const int cg = tid & 31, rg = tid >> 5;
  const int j0 = cg * 4, r0 = rg * 4;

  float acc[4][4];
#pragma unroll
  for (int rr = 0; rr < 4; ++rr)
#pragma unroll
    for (int cc = 0; cc < 4; ++cc) acc[rr][cc] = 0.f;

#pragma unroll 4
  for (int k = 0; k < NDIM; ++k) {
    const float4 w = *(const float4*)&Ws[k][j0];
    const float wv[4] = {w.x, w.y, w.z, w.w};
    const float xx[4] = {Xs[r0 + 0][k], Xs[r0 + 1][k], Xs[r0 + 2][k], Xs[r0 + 3][k]};
#pragma unroll
    for (int rr = 0; rr < 4; ++rr)
#pragma unroll
      for (int cc = 0; cc < 4; ++cc)
        acc[rr][cc] = fmaf(xx[rr], wv[cc], acc[rr][cc]);
  }

  const float4 bv = *(const float4*)&B[j0];
  const float bb[4] = {bv.x, bv.y, bv.z, bv.w};
#pragma unroll
  for (int rr = 0; rr < 4; ++rr) {
    int gr = row0 + r0 + rr;
    ushort4 ho, lo_;
    float v0 = acc[rr][0] + bb[0], v1 = acc[rr][1] + bb[1];
    float v2 = acc[rr][2] + bb[2], v3 = acc[rr][3] + bb[3];
    ho.x = f2bf(v0); lo_.x = f2bf(v0 - bf2f(ho.x));
    ho.y = f2bf(v1); lo_.y = f2bf(v1 - bf2f(ho.y));
    ho.z = f2bf(v2); lo_.z = f2bf(v2 - bf2f(ho.z));
    ho.w = f2bf(v3); lo_.w = f2bf(v3 - bf2f(ho.w));
    *(ushort4*)&Yh[(size_t)gr * HID + j0] = ho;
    *(ushort4*)&Yl[(size_t)gr * HID + j0] = lo_;
  }
}

// ---------------------------------------------------------------------------
// Weight prep: W [128][128] fp32 -> MFMA B-fragment-ordered bf16 hi/lo.
__global__ __launch_bounds__(256) void wprep(const float* __restrict__ n2c_wl,
                                             const float* __restrict__ n2c_wr,
                                             const float* __restrict__ c2n_wl,
                                             const float* __restrict__ c2n_wr,
                                             u16* __restrict__ wp) {
  int gid = blockIdx.x * 256 + threadIdx.x;  // 32768 total
  int lane = gid & 63;
  int t = gid >> 6;                          // 512: m(16) x ks(4) x ct(8)
  int ct = t & 7, ks = (t >> 3) & 3, m = t >> 5;
  const float* Wb;
  switch (m >> 2) {
    case 0: Wb = n2c_wl; break;
    case 1: Wb = n2c_wr; break;
    case 2: Wb = c2n_wl; break;
    default: Wb = c2n_wr; break;
  }
  Wb += (size_t)(m & 3) * HID * HID;
  const int kg = lane >> 4, c = ct * 16 + (lane & 15);
  u16 hi[8], lo[8];
#pragma unroll
  for (int e = 0; e < 8; ++e) {
    float v = Wb[(size_t)(ks * 32 + kg * 8 + e) * HID + c];
    hi[e] = f2bf(v);
    lo[e] = f2bf(v - bf2f(hi[e]));
  }
  size_t base = (size_t)m * 32768 + ((size_t)(ks * 8 + ct) * 64 + lane) * 8;
#pragma unroll
  for (int e = 0; e < 8; ++e) {
    wp[base + e] = hi[e];
    wp[base + 16384 + e] = lo[e];
  }
}

// ---------------------------------------------------------------------------
// MFMA-GEMM v3: 512 threads (8 waves), 128 rows/block, 16 rows/wave.
// The full 64KB packed W (hi+lo) is staged ONCE per block into LDS
// (coalesced 16B/thread), then all B-frag reads are conflict-free
// ds_read_b128 (lane-linear 1KB spans) instead of repeated L2 streams.
// Per-wave compute identical to the R14 16-row version (same numerics).
#define GEMM_STAGE                                                     \
  _Pragma("unroll") for (int q = 0; q < 8; ++q) {                      \
    int i = (tid + q * 512) * 8;                                       \
    *(bf16x8*)&Wl[i] = *(const bf16x8*)&wp[i];                         \
  }

#define GEMM_FRAME                                                     \
  const int lane = tid & 63;                                           \
  const int wv = tid >> 6;                                             \
  const int row0 = blk * 128 + wv * 16;                                \
  const int ri = lane & 15;                                            \
  const int kg = lane >> 4;                                            \
  int r = row0 + ri;                                                   \
  r = r < nrows ? r : nrows - 1;                                       \
  const size_t xbase = (size_t)r * HID + kg * 8;                       \
  bf16x8 Ah[4], Al[4];                                                 \
  _Pragma("unroll") for (int ks = 0; ks < 4; ++ks) {                   \
    Ah[ks] = *(const bf16x8*)&Xh[xbase + ks * 32];                     \
    Al[ks] = *(const bf16x8*)&Xl[xbase + ks * 32];                     \
  }

#define GEMM_CORE                                                                         \
  f32x4 acc[8];                                                                           \
  _Pragma("unroll") for (int ct = 0; ct < 8; ++ct) acc[ct] = (f32x4){0.f, 0.f, 0.f, 0.f}; \
  _Pragma("unroll") for (int ks = 0; ks < 4; ++ks) {                                      \
    const u16* wb = Wl + ((size_t)(ks * 8) * 64 + lane) * 8;                              \
    _Pragma("unroll") for (int ct = 0; ct < 8; ++ct) {                                    \
      bf16x8 Bh = *(const bf16x8*)&wb[ct * 512];                                          \
      bf16x8 Bl = *(const bf16x8*)&wb[16384 + ct * 512];                                  \
      acc[ct] = __builtin_amdgcn_mfma_f32_16x16x32_bf16(Ah[ks], Bh, acc[ct], 0, 0, 0);    \
      acc[ct] = __builtin_amdgcn_mfma_f32_16x16x32_bf16(Al[ks], Bh, acc[ct], 0, 0, 0);    \
      acc[ct] = __builtin_amdgcn_mfma_f32_16x16x32_bf16(Ah[ks], Bl, acc[ct], 0, 0, 0);    \
    }                                                                                     \
  }

#define GEMM_STORE                                                     \
  _Pragma("unroll") for (int ct = 0; ct < 8; ++ct) {                   \
    const float bias = B[ct * 16 + ri];                                \
    _Pragma("unroll") for (int i = 0; i < 4; ++i) {                    \
      int gr = row0 + kg * 4 + i;                                      \
      if (gr < nrows) Y[(size_t)gr * HID + ct * 16 + ri] =             \
          f2bf(acc[ct][i] + bias);                                     \
    }                                                                  \
  }

// Single GEMM, bf16 output.
__global__ __launch_bounds__(512) void gemm_mfma_h(const u16* __restrict__ Xh,
                                                   const u16* __restrict__ Xl,
                                                   const u16* __restrict__ wp,
                                                   const float* __restrict__ B,
                                                   u16* __restrict__ Y, int nrows) {
  __shared__ u16 Wl[32768];  // 64 KB
  const int tid = threadIdx.x;
  const int blk = blockIdx.x;
  GEMM_STAGE
  GEMM_FRAME
  __syncthreads();
  GEMM_CORE
  GEMM_STORE
}

// Dual-GEMM in one launch via grid partition: blocks [0,gbase) compute
// YA = X@WA+BA, blocks [gbase,2*gbase) compute YB = X@WB+BB.
__global__ __launch_bounds__(512) void gemm_mfma_h2(const u16* __restrict__ Xh,
                                                    const u16* __restrict__ Xl,
                                                    const u16* __restrict__ wpA,
                                                    const float* __restrict__ BA,
                                                    u16* __restrict__ YA,
                                                    const u16* __restrict__ wpB,
                                                    const float* __restrict__ BB,
                                                    u16* __restrict__ YB,
                                                    int nrows, int gbase) {
  __shared__ u16 Wl[32768];  // 64 KB
  const int tid = threadIdx.x;
  const bool second = (int)blockIdx.x >= gbase;
  const u16* wp = second ? wpB : wpA;
  const float* B = second ? BB : BA;
  u16* Y = second ? YB : YA;
  const int blk = second ? blockIdx.x - gbase : blockIdx.x;
  GEMM_STAGE
  GEMM_FRAME
  __syncthreads();
  GEMM_CORE
  GEMM_STORE
}

// ---------------------------------------------------------------------------
// CSR build (both graphs per launch): histogram -> scan -> scatter
__global__ void hist2(const int* __restrict__ mdst, const int* __restrict__ cdst,
                      int* __restrict__ cnt_c, int* __restrict__ cnt_n) {
  int e = blockIdx.x * 256 + threadIdx.x;
  if (e < NEDGE) atomicAdd(&cnt_c[mdst[e]], 1);
  else {
    e -= NEDGE;
    if (e < NEDGE) atomicAdd(&cnt_n[cdst[e]], 1);
  }
}

// block bb covers 1024 elements (4/thread); pre[i] = exclusive prefix in block
__global__ __launch_bounds__(256) void scan2(const int* __restrict__ cnt_c,
                                             int* __restrict__ pre_c,
                                             int* __restrict__ bsum_c,
                                             const int* __restrict__ cnt_n,
                                             int* __restrict__ pre_n,
                                             int* __restrict__ bsum_n, int nbC) {
  __shared__ int sdata[256];
  const int b = blockIdx.x, t = threadIdx.x;
  const int* cnt; int* pre; int* bsum; int n; int bb;
  if (b < nbC) { cnt = cnt_c; pre = pre_c; bsum = bsum_c; n = NCLS; bb = b; }
  else { cnt = cnt_n; pre = pre_n; bsum = bsum_n; n = NNODE; bb = b - nbC; }
  const int base = bb * 1024 + t * 4;
  int v[4], s = 0;
#pragma unroll
  for (int q = 0; q < 4; ++q) {
    int i = base + q;
    v[q] = (i < n) ? cnt[i] : 0;
    s += v[q];
  }
  sdata[t] = s;
  __syncthreads();
  for (int off = 1; off < 256; off <<= 1) {
    int y = (t >= off) ? sdata[t - off] : 0;
    __syncthreads();
    sdata[t] += y;
    __syncthreads();
  }
  int run = sdata[t] - s;
  if (t == 255) bsum[bb] = sdata[255];
#pragma unroll
  for (int q = 0; q < 4; ++q) {
    int i = base + q;
    if (i < n) pre[i] = run;
    run += v[q];
  }
}

// 2 blocks: block 0 scans bsum_c (nbC), block 1 bsum_n (nbN); nb <= 128
__global__ __launch_bounds__(128) void scanp2(int* __restrict__ bsum_c, int nbC,
                                              int* __restrict__ bsum_n, int nbN) {
  __shared__ int sd[128];
  int* bs = blockIdx.x ? bsum_n : bsum_c;
  int nb = blockIdx.x ? nbN : nbC;
  int t = threadIdx.x;
  int v = (t < nb) ? bs[t] : 0;
  sd[t] = v;
  __syncthreads();
  for (int off = 1; off < 128; off <<= 1) {
    int y = (t >= off) ? sd[t - off] : 0;
    __syncthreads();
    sd[t] += y;
    __syncthreads();
  }
  if (t < nb) bs[t] = sd[t] - v;  // exclusive
}

__global__ void fin2(const int* __restrict__ pre_c, const int* __restrict__ bsum_c,
                     int* __restrict__ rowptr_c,
                     const int* __restrict__ pre_n, const int* __restrict__ bsum_n,
                     int* __restrict__ rowptr_n) {
  int i = blockIdx.x * 256 + threadIdx.x;
  if (i < NCLS) {
    rowptr_c[i] = pre_c[i] + bsum_c[i >> 10];
    if (i == 0) { rowptr_c[NCLS] = NEDGE; rowptr_n[NNODE] = NEDGE; }
  } else {
    int t = i - NCLS;
    if (t < NNODE) rowptr_n[t] = pre_n[t] + bsum_n[t >> 10];
  }
}

__global__ void scatter2(const int* __restrict__ msrc, const int* __restrict__ mdst,
                         const int* __restrict__ rowptr_c, int* __restrict__ cur_c,
                         int* __restrict__ csr_c,
                         const int* __restrict__ csrc, const int* __restrict__ cdst,
                         const int* __restrict__ rowptr_n, int* __restrict__ cur_n,
                         int* __restrict__ csr_n) {
  int e = blockIdx.x * 256 + threadIdx.x;
  if (e < NEDGE) {
    int d = mdst[e];
    int p = atomicAdd(&cur_c[d], 1);
    csr_c[rowptr_c[d] + p] = msrc[e];
  } else {
    e -= NEDGE;
    if (e < NEDGE) {
      int d = cdst[e];
      int p = atomicAdd(&cur_n[d], 1);
      csr_n[rowptr_n[d] + p] = csrc[e];
    }
  }
}

// ---------------------------------------------------------------------------
// Fused per-dst GATv2: TWO rows per wave, 4-deep edge unroll
// (8 edge-gathers in flight per wave). Lanes 0-31 -> row 2t, 32-63 -> 2t+1;
// 4 channels/lane. Degree mismatch branchless (invalid edges e_=0).
__global__ __launch_bounds__(256) void gat_dst(u16* __restrict__ xh,
                                               u16* __restrict__ xlo,
                                               const u16* __restrict__ flh,    // [n_src][128] bf16
                                               const u16* __restrict__ frh,    // [n_dst][128] bf16
                                               const int* __restrict__ rowptr,
                                               const int* __restrict__ csr_src,
                                               const float* __restrict__ att,  // [128]
                                               const float* __restrict__ bias,
                                               const float* __restrict__ g,
                                               const float* __restrict__ b,
                                               int n_dst) {
  const int wave = threadIdx.x >> 6;     // 0..3
  const int lane = threadIdx.x & 63;
  const int half = lane >> 5;            // row within pair
  const int sub = lane & 31;
  const int j0 = sub * 4;                // channels j0..j0+3; head = sub>>3

  const float4 attv = *(const float4*)&att[j0];
  const float4 bias4 = *(const float4*)&bias[j0];
  const float4 g4 = *(const float4*)&g[j0];
  const float4 b4 = *(const float4*)&b[j0];

  const int npairs = n_dst >> 1;
  const int stride = gridDim.x * 4;
  for (int t = blockIdx.x * 4 + wave; t < npairs; t += stride) {
    const int d = 2 * t + half;
    const ushort4 rr = *(const ushort4*)&frh[(size_t)d * HID + j0];
    const float xr0 = bf2f(rr.x), xr1 = bf2f(rr.y), xr2 = bf2f(rr.z), xr3 = bf2f(rr.w);
    const int e0 = rowptr[d], e1 = rowptr[d + 1];
    const int deg = e1 - e0;
    const int dego = __shfl_xor(deg, 32);
    const int kmax = deg > dego ? deg : dego;

    float a0 = 0.f, a1 = 0.f, a2 = 0.f, a3 = 0.f, den = 0.f;

#define GAT_EDGE(wv, ok)                                              \
    {                                                                 \
      float c0 = bf2f(wv.x), c1 = bf2f(wv.y);                         \
      float c2 = bf2f(wv.z), c3 = bf2f(wv.w);                         \
      float m0 = c0 + xr0; m0 = m0 > 0.f ? m0 : 0.2f * m0;            \
      float m1 = c1 + xr1; m1 = m1 > 0.f ? m1 : 0.2f * m1;            \
      float m2 = c2 + xr2; m2 = m2 > 0.f ? m2 : 0.2f * m2;            \
      float m3 = c3 + xr3; m3 = m3 > 0.f ? m3 : 0.2f * m3;            \
      float p = fmaf(attv.x, m0, fmaf(attv.y, m1,                      \
                fmaf(attv.z, m2, attv.w * m3)));                      \
      p += __shfl_xor(p, 1);                                          \
      p += __shfl_xor(p, 2);                                          \
      p += __shfl_xor(p, 4);                                          \
      float e_ = (ok) ? __expf(p) : 0.f;                              \
      a0 = fmaf(e_, c0, a0); a1 = fmaf(e_, c1, a1);                   \
      a2 = fmaf(e_, c2, a2); a3 = fmaf(e_, c3, a3);                   \
      den += e_;                                                      \
    }

    int k = 0;
    for (; k + 3 < kmax; k += 4) {
      int idx = e0 + k;
      bool ok0 = idx < e1, ok1 = idx + 1 < e1, ok2 = idx + 2 < e1, ok3 = idx + 3 < e1;
      int i0 = min(idx, NEDGE - 1), i1 = min(idx + 1, NEDGE - 1);
      int i2 = min(idx + 2, NEDGE - 1), i3 = min(idx + 3, NEDGE - 1);
      int s0 = csr_src[i0], s1 = csr_src[i1], s2 = csr_src[i2], s3 = csr_src[i3];
      ushort4 w0 = *(const ushort4*)&flh[(size_t)s0 * HID + j0];
      ushort4 w1 = *(const ushort4*)&flh[(size_t)s1 * HID + j0];
      ushort4 w2 = *(const ushort4*)&flh[(size_t)s2 * HID + j0];
      ushort4 w3 = *(const ushort4*)&flh[(size_t)s3 * HID + j0];
      GAT_EDGE(w0, ok0)
      GAT_EDGE(w1, ok1)
      GAT_EDGE(w2, ok2)
      GAT_EDGE(w3, ok3)
    }
    for (; k < kmax; ++k) {
      int idx = e0 + k;
      bool ok0 = idx < e1;
      int i0 = min(idx, NEDGE - 1);
      int s0 = csr_src[i0];
      ushort4 w0 = *(const ushort4*)&flh[(size_t)s0 * HID + j0];
      GAT_EDGE(w0, ok0)
    }
#undef GAT_EDGE

    float rden = (e1 > e0) ? 1.0f / den : 0.f;
    float o0 = a0 * rden, o1 = a1 * rden, o2 = a2 * rden, o3 = a3 * rden;

    // residual from hi/lo state
    const ushort4 hh = *(const ushort4*)&xh[(size_t)d * HID + j0];
    const ushort4 ll = *(const ushort4*)&xlo[(size_t)d * HID + j0];
    float v0 = bf2f(hh.x) + bf2f(ll.x) + o0 + bias4.x;
    float v1 = bf2f(hh.y) + bf2f(ll.y) + o1 + bias4.y;
    float v2 = bf2f(hh.z) + bf2f(ll.z) + o2 + bias4.z;
    float v3 = bf2f(hh.w) + bf2f(ll.w) + o3 + bias4.w;

    // LayerNorm within the 32-lane half (32 lanes x 4 channels = 128)
    float s1 = v0 + v1 + v2 + v3;
    float s2 = v0 * v0 + v1 * v1 + v2 * v2 + v3 * v3;
#pragma unroll
    for (int off = 16; off > 0; off >>= 1) {
      s1 += __shfl_xor(s1, off);
      s2 += __shfl_xor(s2, off);
    }
    const float mu = s1 * (1.0f / HID);
    const float var = s2 * (1.0f / HID) - mu * mu;
    const float inv = rsqrtf(var + 1e-5f);
    float o0n = (v0 - mu) * inv * g4.x + b4.x;
    float o1n = (v1 - mu) * inv * g4.y + b4.y;
    float o2n = (v2 - mu) * inv * g4.z + b4.z;
    float o3n = (v3 - mu) * inv * g4.w + b4.w;

    ushort4 ho, lo_;
    ho.x = f2bf(o0n); lo_.x = f2bf(o0n - bf2f(ho.x));
    ho.y = f2bf(o1n); lo_.y = f2bf(o1n - bf2f(ho.y));
    ho.z = f2bf(o2n); lo_.z = f2bf(o2n - bf2f(ho.z));
    ho.w = f2bf(o3n); lo_.w = f2bf(o3n - bf2f(ho.w));
    *(ushort4*)&xh[(size_t)d * HID + j0] = ho;
    *(ushort4*)&xlo[(size_t)d * HID + j0] = lo_;
  }
}

// ---------------------------------------------------------------------------
__global__ void colsum(const u16* __restrict__ xh, const u16* __restrict__ xlo,
                       float* __restrict__ acc) {
  int j = threadIdx.x;  // 128 threads
  int per = (NCLS + gridDim.x - 1) / gridDim.x;
  int r0 = blockIdx.x * per;
  int r1 = min(r0 + per, NCLS);
  float s = 0.f;
  for (int r = r0; r < r1; ++r)
    s += bf2f(xh[(size_t)r * HID + j]) + bf2f(xlo[(size_t)r * HID + j]);
  atomicAdd(&acc[j], s);
}

__global__ void final_out(const float* __restrict__ acc, float* __restrict__ out) {
  int j = threadIdx.x;
  out[j] = acc[j] * (1.0f / NCLS);
}

// ---------------------------------------------------------------------------
extern "C" void kernel_launch(void* const* d_in, const int* in_sizes, int n_in,
                              void* d_out, int out_size, void* d_ws, size_t ws_size,
                              hipStream_t stream) {
  (void)in_sizes; (void)n_in; (void)out_size; (void)ws_size;
  const float* x_node     = (const float*)d_in[0];
  const float* x_class    = (const float*)d_in[1];
  const int* member_src   = (const int*)d_in[2];
  const int* member_dst   = (const int*)d_in[3];
  const int* contains_src = (const int*)d_in[4];
  const int* contains_dst = (const int*)d_in[5];
  const float* npw = (const float*)d_in[6];
  const float* npb = (const float*)d_in[7];
  const float* cpw = (const float*)d_in[8];
  const float* cpb = (const float*)d_in[9];
  const float* n2c_wl   = (const float*)d_in[10];
  const float* n2c_bl   = (const float*)d_in[11];
  const float* n2c_wr   = (const float*)d_in[12];
  const float* n2c_br   = (const float*)d_in[13];
  const float* n2c_att  = (const float*)d_in[14];
  const float* n2c_bias = (const float*)d_in[15];
  const float* c2n_wl   = (const float*)d_in[16];
  const float* c2n_bl   = (const float*)d_in[17];
  const float* c2n_wr   = (const float*)d_in[18];
  const float* c2n_br   = (const float*)d_in[19];
  const float* c2n_att  = (const float*)d_in[20];
  const float* c2n_bias = (const float*)d_in[21];
  const float* ln_cg = (const float*)d_in[22];
  const float* ln_cb = (const float*)d_in[23];
  const float* ln_ng = (const float*)d_in[24];
  const float* ln_nb = (const float*)d_in[25];

  // workspace layout
  u16* xnh = (u16*)d_ws;                             // NNODE*128 u16
  u16* xnl = xnh + (size_t)NNODE * HID;              // NNODE*128
  u16* xch = xnl + (size_t)NNODE * HID;              // NCLS*128
  u16* xcl = xch + (size_t)NCLS * HID;               // NCLS*128
  u16* flb = xcl + (size_t)NCLS * HID;               // NNODE*128 bf16
  u16* frn = flb + (size_t)NNODE * HID;              // NNODE*128 bf16
  u16* frc = frn + (size_t)NNODE * HID;              // NCLS*128 bf16
  float* accb = (float*)(frc + (size_t)NCLS * HID);  // 128
  int* rowptr_c = (int*)(accb + 128);                // NCLS+1
  int* csr_c    = rowptr_c + (NCLS + 1);             // NEDGE
  int* rowptr_n = csr_c + NEDGE;                     // NNODE+1
  int* csr_n    = rowptr_n + (NNODE + 1);            // NEDGE
  int* cnt_c    = csr_n + NEDGE;                     // NCLS (cnt_c..cur_n contiguous, 1 memset)
  int* cur_c    = cnt_c + NCLS;                      // NCLS
  int* cnt_n    = cur_c + NCLS;                      // NNODE
  int* cur_n    = cnt_n + NNODE;                     // NNODE
  int* pre_c    = cur_n + NNODE;                     // NCLS
  int* pre_n    = pre_c + NCLS;                      // NNODE
  int* bsum_c   = pre_n + NNODE;                     // 128
  int* bsum_n   = bsum_c + 128;                      // 128
  // packed weights overlay cnt/cursor region after CSR build (1 MB <= 1.2 MB)
  u16* wp = (u16*)cnt_c;

  const int nbC = (NCLS + 1023) / 1024;   // 49
  const int nbN = (NNODE + 1023) / 1024;  // 98
  const int EB2 = (2 * NEDGE + 255) / 256;
  const int GAT_BLOCKS = 2048;  // persistent: 2048 blocks x 4 waves, 2 rows/wave
  const int GB_N = (NNODE + 127) / 128;   // 128 rows/block (512 threads)
  const int GB_C = (NCLS + 127) / 128;

  // ---- initial projections (write hi/lo state) ----
  proj_node<<<NNODE / 32, 256, 0, stream>>>(x_node, npw, npb, xnh, xnl);
  proj_kernel<<<(NCLS * HID + 255) / 256, 256, 0, stream>>>(x_class, cpw, cpb, xch, xcl, NCLS, CDIM);

  // ---- CSR build (both graphs per launch) ----
  hipMemsetAsync(cnt_c, 0, (size_t)(2 * NCLS + 2 * NNODE) * sizeof(int), stream);
  hist2<<<EB2, 256, 0, stream>>>(member_dst, contains_dst, cnt_c, cnt_n);
  scan2<<<nbC + nbN, 256, 0, stream>>>(cnt_c, pre_c, bsum_c, cnt_n, pre_n, bsum_n, nbC);
  scanp2<<<2, 128, 0, stream>>>(bsum_c, nbC, bsum_n, nbN);
  fin2<<<(NCLS + NNODE + 255) / 256, 256, 0, stream>>>(pre_c, bsum_c, rowptr_c,
                                                       pre_n, bsum_n, rowptr_n);
  scatter2<<<EB2, 256, 0, stream>>>(member_src, member_dst, rowptr_c, cur_c, csr_c,
                                    contains_src, contains_dst, rowptr_n, cur_n, csr_n);

  // ---- pack weights (cnt/cursor region dead now) ----
  wprep<<<128, 256, 0, stream>>>(n2c_wl, n2c_wr, c2n_wl, c2n_wr, wp);

  // prologue: frc = xc @ n2c_wr[0] + br[0]
  gemm_mfma_h<<<GB_C, 512, 0, stream>>>(xch, xcl, wp + (size_t)4 * 32768,
                                        n2c_br, frc, NCLS);

  // ---- layers ----
  for (int l = 0; l < NLAY; ++l) {
    // node-side dual launch: flb = xn @ n2c_wl[l]; frn = xn @ c2n_wr[l]
    gemm_mfma_h2<<<2 * GB_N, 512, 0, stream>>>(xnh, xnl,
                                               wp + (size_t)(0 + l) * 32768, n2c_bl + l * HID, flb,
                                               wp + (size_t)(12 + l) * 32768, c2n_br + l * HID, frn,
                                               NNODE, GB_N);
    // n2c gat: dst=class
    gat_dst<<<GAT_BLOCKS, 256, 0, stream>>>(xch, xcl, flb, frc, rowptr_c, csr_c,
                                            n2c_att + l * HID, n2c_bias + l * HID,
                                            ln_cg + l * HID, ln_cb + l * HID, NCLS);
    // class-side: flb = xc @ c2n_wl[l]; frc = xc @ n2c_wr[l+1] (when it exists)
    if (l < NLAY - 1) {
      gemm_mfma_h2<<<2 * GB_C, 512, 0, stream>>>(xch, xcl,
                                                 wp + (size_t)(8 + l) * 32768, c2n_bl + l * HID, flb,
                                                 wp + (size_t)(4 + l + 1) * 32768, n2c_br + (l + 1) * HID, frc,
                                                 NCLS, GB_C);
    } else {
      gemm_mfma_h<<<GB_C, 512, 0, stream>>>(xch, xcl, wp + (size_t)(8 + l) * 32768,
                                            c2n_bl + l * HID, flb, NCLS);
    }
    // c2n gat: dst=node
    gat_dst<<<GAT_BLOCKS, 256, 0, stream>>>(xnh, xnl, flb, frn, rowptr_n, csr_n,
                                            c2n_att + l * HID, c2n_bias + l * HID,
                                            ln_ng + l * HID, ln_nb + l * HID, NNODE);
  }

  hipMemsetAsync(accb, 0, HID * sizeof(float), stream);
  colsum<<<256, HID, 0, stream>>>(xch, xcl, accb);
  final_out<<<1, 128, 0, stream>>>(accb, (float*)d_out);
}

// Round 20
// 896.098 us; speedup vs baseline: 1.1847x; 1.0485x over previous
//
#include <hip/hip_runtime.h>

#define NNODE 100000
#define NCLS  50000
#define NEDGE 400000
#define NDIM  43
#define CDIM  2
#define HID   128
#define NHEAD 4
#define CHN   32
#define NLAY  4

typedef unsigned short u16;
typedef unsigned int u32;
typedef __attribute__((ext_vector_type(8))) short bf16x8;
typedef __attribute__((ext_vector_type(4))) float f32x4;

// fp32 -> bf16 round-to-nearest-even
__device__ __forceinline__ u16 f2bf(float f) {
  u32 u = __float_as_uint(f);
  return (u16)((u + 0x7FFFu + ((u >> 16) & 1u)) >> 16);
}
__device__ __forceinline__ float bf2f(u16 h) {
  return __uint_as_float(((u32)h) << 16);
}

// ---------------------------------------------------------------------------
// Class projection (K=2): writes hi/lo bf16 state arrays.
__global__ void proj_kernel(const float* __restrict__ X, const float* __restrict__ W,
                            const float* __restrict__ B, u16* __restrict__ Yh,
                            u16* __restrict__ Yl, int nrows, int K) {
  int t = blockIdx.x * blockDim.x + threadIdx.x;
  if (t >= nrows * HID) return;
  int i = t >> 7, j = t & (HID - 1);
  float acc = B[j];
  for (int k = 0; k < K; ++k)
    acc = fmaf(X[i * K + k], W[k * HID + j], acc);
  u16 h = f2bf(acc);
  Yh[t] = h;
  Yl[t] = f2bf(acc - bf2f(h));
}

// ---------------------------------------------------------------------------
// Node projection, K=43, LDS-tiled. Writes hi/lo bf16 state arrays.
__global__ __launch_bounds__(256) void proj_node(const float* __restrict__ X,
                                                 const float* __restrict__ W,
                                                 const float* __restrict__ B,
                                                 u16* __restrict__ Yh,
                                                 u16* __restrict__ Yl) {
  __shared__ float Ws[NDIM][HID];   // 22016 B, [k][j]
  __shared__ float Xs[32][NDIM];    // 5504 B,  [r][k]
  const int tid = threadIdx.x;
  const int row0 = blockIdx.x * 32;

  for (int i = tid; i < NDIM * (HID / 4); i += 256) {
    int k = i >> 5, j4 = (i & 31) << 2;
    *(float4*)&Ws[k][j4] = *(const float4*)&W[(size_t)k * HID + j4];
  }
  const float* Xb = X + (size_t)row0 * NDIM;
  for (int i = tid; i < 32 * NDIM; i += 256) ((float*)Xs)[i] = Xb[i];
  __syncthreads();

  const int cg = tid & 31, rg = tid >> 5;
  const int j0 = cg * 4, r0 = rg * 4;

  float acc[4][4];
#pragma unroll
  for (int rr = 0; rr < 4; ++rr)
#pragma unroll
    for (int cc = 0; cc < 4; ++cc) acc[rr][cc] = 0.f;

#pragma unroll 4
  for (int k = 0; k < NDIM; ++k) {
    const float4 w = *(const float4*)&Ws[k][j0];
    const float wv[4] = {w.x, w.y, w.z, w.w};
    const float xx[4] = {Xs[r0 + 0][k], Xs[r0 + 1][k], Xs[r0 + 2][k], Xs[r0 + 3][k]};
#pragma unroll
    for (int rr = 0; rr < 4; ++rr)
#pragma unroll
      for (int cc = 0; cc < 4; ++cc)
        acc[rr][cc] = fmaf(xx[rr], wv[cc], acc[rr][cc]);
  }

  const float4 bv = *(const float4*)&B[j0];
  const float bb[4] = {bv.x, bv.y, bv.z, bv.w};
#pragma unroll
  for (int rr = 0; rr < 4; ++rr) {
    int gr = row0 + r0 + rr;
    ushort4 ho, lo_;
    float v0 = acc[rr][0] + bb[0], v1 = acc[rr][1] + bb[1];
    float v2 = acc[rr][2] + bb[2], v3 = acc[rr][3] + bb[3];
    ho.x = f2bf(v0); lo_.x = f2bf(v0 - bf2f(ho.x));
    ho.y = f2bf(v1); lo_.y = f2bf(v1 - bf2f(ho.y));
    ho.z = f2bf(v2); lo_.z = f2bf(v2 - bf2f(ho.z));
    ho.w = f2bf(v3); lo_.w = f2bf(v3 - bf2f(ho.w));
    *(ushort4*)&Yh[(size_t)gr * HID + j0] = ho;
    *(ushort4*)&Yl[(size_t)gr * HID + j0] = lo_;
  }
}

// ---------------------------------------------------------------------------
// Weight prep: W [128][128] fp32 -> MFMA B-fragment-ordered bf16 hi/lo.
__global__ __launch_bounds__(256) void wprep(const float* __restrict__ n2c_wl,
                                             const float* __restrict__ n2c_wr,
                                             const float* __restrict__ c2n_wl,
                                             const float* __restrict__ c2n_wr,
                                             u16* __restrict__ wp) {
  int gid = blockIdx.x * 256 + threadIdx.x;  // 32768 total
  int lane = gid & 63;
  int t = gid >> 6;                          // 512: m(16) x ks(4) x ct(8)
  int ct = t & 7, ks = (t >> 3) & 3, m = t >> 5;
  const float* Wb;
  switch (m >> 2) {
    case 0: Wb = n2c_wl; break;
    case 1: Wb = n2c_wr; break;
    case 2: Wb = c2n_wl; break;
    default: Wb = c2n_wr; break;
  }
  Wb += (size_t)(m & 3) * HID * HID;
  const int kg = lane >> 4, c = ct * 16 + (lane & 15);
  u16 hi[8], lo[8];
#pragma unroll
  for (int e = 0; e < 8; ++e) {
    float v = Wb[(size_t)(ks * 32 + kg * 8 + e) * HID + c];
    hi[e] = f2bf(v);
    lo[e] = f2bf(v - bf2f(hi[e]));
  }
  size_t base = (size_t)m * 32768 + ((size_t)(ks * 8 + ct) * 64 + lane) * 8;
#pragma unroll
  for (int e = 0; e < 8; ++e) {
    wp[base + e] = hi[e];
    wp[base + 16384 + e] = lo[e];
  }
}

// ---------------------------------------------------------------------------
// MFMA-GEMM v3: 512 threads (8 waves), 128 rows/block, 16 rows/wave.
// The full 64KB packed W (hi+lo) is staged ONCE per block into LDS
// (coalesced 16B/thread), then all B-frag reads are conflict-free
// ds_read_b128 (lane-linear 1KB spans) instead of repeated L2 streams.
#define GEMM_STAGE                                                     \
  _Pragma("unroll") for (int q = 0; q < 8; ++q) {                      \
    int i = (tid + q * 512) * 8;                                       \
    *(bf16x8*)&Wl[i] = *(const bf16x8*)&wp[i];                         \
  }

#define GEMM_FRAME                                                     \
  const int lane = tid & 63;                                           \
  const int wv = tid >> 6;                                             \
  const int row0 = blk * 128 + wv * 16;                                \
  const int ri = lane & 15;                                            \
  const int kg = lane >> 4;                                            \
  int r = row0 + ri;                                                   \
  r = r < nrows ? r : nrows - 1;                                       \
  const size_t xbase = (size_t)r * HID + kg * 8;                       \
  bf16x8 Ah[4], Al[4];                                                 \
  _Pragma("unroll") for (int ks = 0; ks < 4; ++ks) {                   \
    Ah[ks] = *(const bf16x8*)&Xh[xbase + ks * 32];                     \
    Al[ks] = *(const bf16x8*)&Xl[xbase + ks * 32];                     \
  }

#define GEMM_CORE                                                                         \
  f32x4 acc[8];                                                                           \
  _Pragma("unroll") for (int ct = 0; ct < 8; ++ct) acc[ct] = (f32x4){0.f, 0.f, 0.f, 0.f}; \
  _Pragma("unroll") for (int ks = 0; ks < 4; ++ks) {                                      \
    const u16* wb = Wl + ((size_t)(ks * 8) * 64 + lane) * 8;                              \
    _Pragma("unroll") for (int ct = 0; ct < 8; ++ct) {                                    \
      bf16x8 Bh = *(const bf16x8*)&wb[ct * 512];                                          \
      bf16x8 Bl = *(const bf16x8*)&wb[16384 + ct * 512];                                  \
      acc[ct] = __builtin_amdgcn_mfma_f32_16x16x32_bf16(Ah[ks], Bh, acc[ct], 0, 0, 0);    \
      acc[ct] = __builtin_amdgcn_mfma_f32_16x16x32_bf16(Al[ks], Bh, acc[ct], 0, 0, 0);    \
      acc[ct] = __builtin_amdgcn_mfma_f32_16x16x32_bf16(Ah[ks], Bl, acc[ct], 0, 0, 0);    \
    }                                                                                     \
  }

#define GEMM_STORE                                                     \
  _Pragma("unroll") for (int ct = 0; ct < 8; ++ct) {                   \
    const float bias = B[ct * 16 + ri];                                \
    _Pragma("unroll") for (int i = 0; i < 4; ++i) {                    \
      int gr = row0 + kg * 4 + i;                                      \
      if (gr < nrows) Y[(size_t)gr * HID + ct * 16 + ri] =             \
          f2bf(acc[ct][i] + bias);                                     \
    }                                                                  \
  }

// Single GEMM, bf16 output.
__global__ __launch_bounds__(512) void gemm_mfma_h(const u16* __restrict__ Xh,
                                                   const u16* __restrict__ Xl,
                                                   const u16* __restrict__ wp,
                                                   const float* __restrict__ B,
                                                   u16* __restrict__ Y, int nrows) {
  __shared__ u16 Wl[32768];  // 64 KB
  const int tid = threadIdx.x;
  const int blk = blockIdx.x;
  GEMM_STAGE
  GEMM_FRAME
  __syncthreads();
  GEMM_CORE
  GEMM_STORE
}

// Dual-GEMM in one launch via grid partition.
__global__ __launch_bounds__(512) void gemm_mfma_h2(const u16* __restrict__ Xh,
                                                    const u16* __restrict__ Xl,
                                                    const u16* __restrict__ wpA,
                                                    const float* __restrict__ BA,
                                                    u16* __restrict__ YA,
                                                    const u16* __restrict__ wpB,
                                                    const float* __restrict__ BB,
                                                    u16* __restrict__ YB,
                                                    int nrows, int gbase) {
  __shared__ u16 Wl[32768];  // 64 KB
  const int tid = threadIdx.x;
  const bool second = (int)blockIdx.x >= gbase;
  const u16* wp = second ? wpB : wpA;
  const float* B = second ? BB : BA;
  u16* Y = second ? YB : YA;
  const int blk = second ? blockIdx.x - gbase : blockIdx.x;
  GEMM_STAGE
  GEMM_FRAME
  __syncthreads();
  GEMM_CORE
  GEMM_STORE
}

// ---------------------------------------------------------------------------
// CSR build (both graphs per launch): histogram -> scan -> scatter
__global__ void hist2(const int* __restrict__ mdst, const int* __restrict__ cdst,
                      int* __restrict__ cnt_c, int* __restrict__ cnt_n) {
  int e = blockIdx.x * 256 + threadIdx.x;
  if (e < NEDGE) atomicAdd(&cnt_c[mdst[e]], 1);
  else {
    e -= NEDGE;
    if (e < NEDGE) atomicAdd(&cnt_n[cdst[e]], 1);
  }
}

// block bb covers 1024 elements (4/thread); pre[i] = exclusive prefix in block
__global__ __launch_bounds__(256) void scan2(const int* __restrict__ cnt_c,
                                             int* __restrict__ pre_c,
                                             int* __restrict__ bsum_c,
                                             const int* __restrict__ cnt_n,
                                             int* __restrict__ pre_n,
                                             int* __restrict__ bsum_n, int nbC) {
  __shared__ int sdata[256];
  const int b = blockIdx.x, t = threadIdx.x;
  const int* cnt; int* pre; int* bsum; int n; int bb;
  if (b < nbC) { cnt = cnt_c; pre = pre_c; bsum = bsum_c; n = NCLS; bb = b; }
  else { cnt = cnt_n; pre = pre_n; bsum = bsum_n; n = NNODE; bb = b - nbC; }
  const int base = bb * 1024 + t * 4;
  int v[4], s = 0;
#pragma unroll
  for (int q = 0; q < 4; ++q) {
    int i = base + q;
    v[q] = (i < n) ? cnt[i] : 0;
    s += v[q];
  }
  sdata[t] = s;
  __syncthreads();
  for (int off = 1; off < 256; off <<= 1) {
    int y = (t >= off) ? sdata[t - off] : 0;
    __syncthreads();
    sdata[t] += y;
    __syncthreads();
  }
  int run = sdata[t] - s;
  if (t == 255) bsum[bb] = sdata[255];
#pragma unroll
  for (int q = 0; q < 4; ++q) {
    int i = base + q;
    if (i < n) pre[i] = run;
    run += v[q];
  }
}

// 2 blocks: block 0 scans bsum_c (nbC), block 1 bsum_n (nbN); nb <= 128
__global__ __launch_bounds__(128) void scanp2(int* __restrict__ bsum_c, int nbC,
                                              int* __restrict__ bsum_n, int nbN) {
  __shared__ int sd[128];
  int* bs = blockIdx.x ? bsum_n : bsum_c;
  int nb = blockIdx.x ? nbN : nbC;
  int t = threadIdx.x;
  int v = (t < nb) ? bs[t] : 0;
  sd[t] = v;
  __syncthreads();
  for (int off = 1; off < 128; off <<= 1) {
    int y = (t >= off) ? sd[t - off] : 0;
    __syncthreads();
    sd[t] += y;
    __syncthreads();
  }
  if (t < nb) bs[t] = sd[t] - v;  // exclusive
}

__global__ void fin2(const int* __restrict__ pre_c, const int* __restrict__ bsum_c,
                     int* __restrict__ rowptr_c,
                     const int* __restrict__ pre_n, const int* __restrict__ bsum_n,
                     int* __restrict__ rowptr_n) {
  int i = blockIdx.x * 256 + threadIdx.x;
  if (i < NCLS) {
    rowptr_c[i] = pre_c[i] + bsum_c[i >> 10];
    if (i == 0) { rowptr_c[NCLS] = NEDGE; rowptr_n[NNODE] = NEDGE; }
  } else {
    int t = i - NCLS;
    if (t < NNODE) rowptr_n[t] = pre_n[t] + bsum_n[t >> 10];
  }
}

__global__ void scatter2(const int* __restrict__ msrc, const int* __restrict__ mdst,
                         const int* __restrict__ rowptr_c, int* __restrict__ cur_c,
                         int* __restrict__ csr_c,
                         const int* __restrict__ csrc, const int* __restrict__ cdst,
                         const int* __restrict__ rowptr_n, int* __restrict__ cur_n,
                         int* __restrict__ csr_n) {
  int e = blockIdx.x * 256 + threadIdx.x;
  if (e < NEDGE) {
    int d = mdst[e];
    int p = atomicAdd(&cur_c[d], 1);
    csr_c[rowptr_c[d] + p] = msrc[e];
  } else {
    e -= NEDGE;
    if (e < NEDGE) {
      int d = cdst[e];
      int p = atomicAdd(&cur_n[d], 1);
      csr_n[rowptr_n[d] + p] = csrc[e];
    }
  }
}

// ---------------------------------------------------------------------------
// Fused per-dst GATv2: TWO rows per wave, 4-deep edge unroll
// (8 edge-gathers in flight per wave). Lanes 0-31 -> row 2t, 32-63 -> 2t+1;
// 4 channels/lane. Degree mismatch branchless (invalid edges e_=0).
__global__ __launch_bounds__(256) void gat_dst(u16* __restrict__ xh,
                                               u16* __restrict__ xlo,
                                               const u16* __restrict__ flh,    // [n_src][128] bf16
                                               const u16* __restrict__ frh,    // [n_dst][128] bf16
                                               const int* __restrict__ rowptr,
                                               const int* __restrict__ csr_src,
                                               const float* __restrict__ att,  // [128]
                                               const float* __restrict__ bias,
                                               const float* __restrict__ g,
                                               const float* __restrict__ b,
                                               int n_dst) {
  const int wave = threadIdx.x >> 6;     // 0..3
  const int lane = threadIdx.x & 63;
  const int half = lane >> 5;            // row within pair
  const int sub = lane & 31;
  const int j0 = sub * 4;                // channels j0..j0+3; head = sub>>3

  const float4 attv = *(const float4*)&att[j0];
  const float4 bias4 = *(const float4*)&bias[j0];
  const float4 g4 = *(const float4*)&g[j0];
  const float4 b4 = *(const float4*)&b[j0];

  const int npairs = n_dst >> 1;
  const int stride = gridDim.x * 4;
  for (int t = blockIdx.x * 4 + wave; t < npairs; t += stride) {
    const int d = 2 * t + half;
    const ushort4 rr = *(const ushort4*)&frh[(size_t)d * HID + j0];
    const float xr0 = bf2f(rr.x), xr1 = bf2f(rr.y), xr2 = bf2f(rr.z), xr3 = bf2f(rr.w);
    const int e0 = rowptr[d], e1 = rowptr[d + 1];
    const int deg = e1 - e0;
    const int dego = __shfl_xor(deg, 32);
    const int kmax = deg > dego ? deg : dego;

    float a0 = 0.f, a1 = 0.f, a2 = 0.f, a3 = 0.f, den = 0.f;

#define GAT_EDGE(wv, ok)                                              \
    {                                                                 \
      float c0 = bf2f(wv.x), c1 = bf2f(wv.y);                         \
      float c2 = bf2f(wv.z), c3 = bf2f(wv.w);                         \
      float m0 = c0 + xr0; m0 = m0 > 0.f ? m0 : 0.2f * m0;            \
      float m1 = c1 + xr1; m1 = m1 > 0.f ? m1 : 0.2f * m1;            \
      float m2 = c2 + xr2; m2 = m2 > 0.f ? m2 : 0.2f * m2;            \
      float m3 = c3 + xr3; m3 = m3 > 0.f ? m3 : 0.2f * m3;            \
      float p = fmaf(attv.x, m0, fmaf(attv.y, m1,                      \
                fmaf(attv.z, m2, attv.w * m3)));                      \
      p += __shfl_xor(p, 1);                                          \
      p += __shfl_xor(p, 2);                                          \
      p += __shfl_xor(p, 4);                                          \
      float e_ = (ok) ? __expf(p) : 0.f;                              \
      a0 = fmaf(e_, c0, a0); a1 = fmaf(e_, c1, a1);                   \
      a2 = fmaf(e_, c2, a2); a3 = fmaf(e_, c3, a3);                   \
      den += e_;                                                      \
    }

    int k = 0;
    for (; k + 3 < kmax; k += 4) {
      int idx = e0 + k;
      bool ok0 = idx < e1, ok1 = idx + 1 < e1, ok2 = idx + 2 < e1, ok3 = idx + 3 < e1;
      int i0 = min(idx, NEDGE - 1), i1 = min(idx + 1, NEDGE - 1);
      int i2 = min(idx + 2, NEDGE - 1), i3 = min(idx + 3, NEDGE - 1);
      int s0 = csr_src[i0], s1 = csr_src[i1], s2 = csr_src[i2], s3 = csr_src[i3];
      ushort4 w0 = *(const ushort4*)&flh[(size_t)s0 * HID + j0];
      ushort4 w1 = *(const ushort4*)&flh[(size_t)s1 * HID + j0];
      ushort4 w2 = *(const ushort4*)&flh[(size_t)s2 * HID + j0];
      ushort4 w3 = *(const ushort4*)&flh[(size_t)s3 * HID + j0];
      GAT_EDGE(w0, ok0)
      GAT_EDGE(w1, ok1)
      GAT_EDGE(w2, ok2)
      GAT_EDGE(w3, ok3)
    }
    for (; k < kmax; ++k) {
      int idx = e0 + k;
      bool ok0 = idx < e1;
      int i0 = min(idx, NEDGE - 1);
      int s0 = csr_src[i0];
      ushort4 w0 = *(const ushort4*)&flh[(size_t)s0 * HID + j0];
      GAT_EDGE(w0, ok0)
    }
#undef GAT_EDGE

    float rden = (e1 > e0) ? 1.0f / den : 0.f;
    float o0 = a0 * rden, o1 = a1 * rden, o2 = a2 * rden, o3 = a3 * rden;

    // residual from hi/lo state
    const ushort4 hh = *(const ushort4*)&xh[(size_t)d * HID + j0];
    const ushort4 ll = *(const ushort4*)&xlo[(size_t)d * HID + j0];
    float v0 = bf2f(hh.x) + bf2f(ll.x) + o0 + bias4.x;
    float v1 = bf2f(hh.y) + bf2f(ll.y) + o1 + bias4.y;
    float v2 = bf2f(hh.z) + bf2f(ll.z) + o2 + bias4.z;
    float v3 = bf2f(hh.w) + bf2f(ll.w) + o3 + bias4.w;

    // LayerNorm within the 32-lane half (32 lanes x 4 channels = 128)
    float s1 = v0 + v1 + v2 + v3;
    float s2 = v0 * v0 + v1 * v1 + v2 * v2 + v3 * v3;
#pragma unroll
    for (int off = 16; off > 0; off >>= 1) {
      s1 += __shfl_xor(s1, off);
      s2 += __shfl_xor(s2, off);
    }
    const float mu = s1 * (1.0f / HID);
    const float var = s2 * (1.0f / HID) - mu * mu;
    const float inv = rsqrtf(var + 1e-5f);
    float o0n = (v0 - mu) * inv * g4.x + b4.x;
    float o1n = (v1 - mu) * inv * g4.y + b4.y;
    float o2n = (v2 - mu) * inv * g4.z + b4.z;
    float o3n = (v3 - mu) * inv * g4.w + b4.w;

    ushort4 ho, lo_;
    ho.x = f2bf(o0n); lo_.x = f2bf(o0n - bf2f(ho.x));
    ho.y = f2bf(o1n); lo_.y = f2bf(o1n - bf2f(ho.y));
    ho.z = f2bf(o2n); lo_.z = f2bf(o2n - bf2f(ho.z));
    ho.w = f2bf(o3n); lo_.w = f2bf(o3n - bf2f(ho.w));
    *(ushort4*)&xh[(size_t)d * HID + j0] = ho;
    *(ushort4*)&xlo[(size_t)d * HID + j0] = lo_;
  }
}

// ---------------------------------------------------------------------------
// colsum v2: vectorized + latency-hiding. 512 blocks x 256 threads.
// Thread t: channel group cg = t&15 (8 channels, 16B loads), row stream
// t>>4; a 16-thread group covers one full 256B row; a wave covers 4
// consecutive rows (1KB contiguous). LDS-reduce 16 streams, then 128
// atomics per block.
__global__ __launch_bounds__(256) void colsum(const u16* __restrict__ xh,
                                              const u16* __restrict__ xlo,
                                              float* __restrict__ acc) {
  const int t = threadIdx.x;
  const int cg = t & 15;
  const int c0 = cg * 8;
  float s[8];
#pragma unroll
  for (int e = 0; e < 8; ++e) s[e] = 0.f;

  const int stride = gridDim.x * 16;
  for (int r = blockIdx.x * 16 + (t >> 4); r < NCLS; r += stride) {
    const u16* ph = &xh[(size_t)r * HID + c0];
    const u16* pl = &xlo[(size_t)r * HID + c0];
    ushort4 h0 = *(const ushort4*)ph;
    ushort4 h1 = *(const ushort4*)(ph + 4);
    ushort4 l0 = *(const ushort4*)pl;
    ushort4 l1 = *(const ushort4*)(pl + 4);
    s[0] += bf2f(h0.x) + bf2f(l0.x);
    s[1] += bf2f(h0.y) + bf2f(l0.y);
    s[2] += bf2f(h0.z) + bf2f(l0.z);
    s[3] += bf2f(h0.w) + bf2f(l0.w);
    s[4] += bf2f(h1.x) + bf2f(l1.x);
    s[5] += bf2f(h1.y) + bf2f(l1.y);
    s[6] += bf2f(h1.z) + bf2f(l1.z);
    s[7] += bf2f(h1.w) + bf2f(l1.w);
  }

  __shared__ float red[256][8];  // 8 KB
#pragma unroll
  for (int e = 0; e < 8; ++e) red[t][e] = s[e];
  __syncthreads();
  if (t < 128) {
    int cg2 = t >> 3, e = t & 7;
    float sum = 0.f;
#pragma unroll
    for (int st = 0; st < 16; ++st) sum += red[st * 16 + cg2][e];
    atomicAdd(&acc[cg2 * 8 + e], sum);
  }
}

__global__ void final_out(const float* __restrict__ acc, float* __restrict__ out) {
  int j = threadIdx.x;
  out[j] = acc[j] * (1.0f / NCLS);
}

// ---------------------------------------------------------------------------
extern "C" void kernel_launch(void* const* d_in, const int* in_sizes, int n_in,
                              void* d_out, int out_size, void* d_ws, size_t ws_size,
                              hipStream_t stream) {
  (void)in_sizes; (void)n_in; (void)out_size; (void)ws_size;
  const float* x_node     = (const float*)d_in[0];
  const float* x_class    = (const float*)d_in[1];
  const int* member_src   = (const int*)d_in[2];
  const int* member_dst   = (const int*)d_in[3];
  const int* contains_src = (const int*)d_in[4];
  const int* contains_dst = (const int*)d_in[5];
  const float* npw = (const float*)d_in[6];
  const float* npb = (const float*)d_in[7];
  const float* cpw = (const float*)d_in[8];
  const float* cpb = (const float*)d_in[9];
  const float* n2c_wl   = (const float*)d_in[10];
  const float* n2c_bl   = (const float*)d_in[11];
  const float* n2c_wr   = (const float*)d_in[12];
  const float* n2c_br   = (const float*)d_in[13];
  const float* n2c_att  = (const float*)d_in[14];
  const float* n2c_bias = (const float*)d_in[15];
  const float* c2n_wl   = (const float*)d_in[16];
  const float* c2n_bl   = (const float*)d_in[17];
  const float* c2n_wr   = (const float*)d_in[18];
  const float* c2n_br   = (const float*)d_in[19];
  const float* c2n_att  = (const float*)d_in[20];
  const float* c2n_bias = (const float*)d_in[21];
  const float* ln_cg = (const float*)d_in[22];
  const float* ln_cb = (const float*)d_in[23];
  const float* ln_ng = (const float*)d_in[24];
  const float* ln_nb = (const float*)d_in[25];

  // workspace layout
  u16* xnh = (u16*)d_ws;                             // NNODE*128 u16
  u16* xnl = xnh + (size_t)NNODE * HID;              // NNODE*128
  u16* xch = xnl + (size_t)NNODE * HID;              // NCLS*128
  u16* xcl = xch + (size_t)NCLS * HID;               // NCLS*128
  u16* flb = xcl + (size_t)NCLS * HID;               // NNODE*128 bf16
  u16* frn = flb + (size_t)NNODE * HID;              // NNODE*128 bf16
  u16* frc = frn + (size_t)NNODE * HID;              // NCLS*128 bf16
  float* accb = (float*)(frc + (size_t)NCLS * HID);  // 128
  int* rowptr_c = (int*)(accb + 128);                // NCLS+1
  int* csr_c    = rowptr_c + (NCLS + 1);             // NEDGE
  int* rowptr_n = csr_c + NEDGE;                     // NNODE+1
  int* csr_n    = rowptr_n + (NNODE + 1);            // NEDGE
  int* cnt_c    = csr_n + NEDGE;                     // NCLS (cnt_c..cur_n contiguous, 1 memset)
  int* cur_c    = cnt_c + NCLS;                      // NCLS
  int* cnt_n    = cur_c + NCLS;                      // NNODE
  int* cur_n    = cnt_n + NNODE;                     // NNODE
  int* pre_c    = cur_n + NNODE;                     // NCLS
  int* pre_n    = pre_c + NCLS;                      // NNODE
  int* bsum_c   = pre_n + NNODE;                     // 128
  int* bsum_n   = bsum_c + 128;                      // 128
  // packed weights overlay cnt/cursor region after CSR build (1 MB <= 1.2 MB)
  u16* wp = (u16*)cnt_c;

  const int nbC = (NCLS + 1023) / 1024;   // 49
  const int nbN = (NNODE + 1023) / 1024;  // 98
  const int EB2 = (2 * NEDGE + 255) / 256;
  const int GAT_BLOCKS = 2048;  // persistent: 2048 blocks x 4 waves, 2 rows/wave
  const int GB_N = (NNODE + 127) / 128;   // 128 rows/block (512 threads)
  const int GB_C = (NCLS + 127) / 128;

  // ---- initial projections (write hi/lo state) ----
  proj_node<<<NNODE / 32, 256, 0, stream>>>(x_node, npw, npb, xnh, xnl);
  proj_kernel<<<(NCLS * HID + 255) / 256, 256, 0, stream>>>(x_class, cpw, cpb, xch, xcl, NCLS, CDIM);

  // ---- CSR build (both graphs per launch) ----
  hipMemsetAsync(cnt_c, 0, (size_t)(2 * NCLS + 2 * NNODE) * sizeof(int), stream);
  hist2<<<EB2, 256, 0, stream>>>(member_dst, contains_dst, cnt_c, cnt_n);
  scan2<<<nbC + nbN, 256, 0, stream>>>(cnt_c, pre_c, bsum_c, cnt_n, pre_n, bsum_n, nbC);
  scanp2<<<2, 128, 0, stream>>>(bsum_c, nbC, bsum_n, nbN);
  fin2<<<(NCLS + NNODE + 255) / 256, 256, 0, stream>>>(pre_c, bsum_c, rowptr_c,
                                                       pre_n, bsum_n, rowptr_n);
  scatter2<<<EB2, 256, 0, stream>>>(member_src, member_dst, rowptr_c, cur_c, csr_c,
                                    contains_src, contains_dst, rowptr_n, cur_n, csr_n);

  // ---- pack weights (cnt/cursor region dead now) ----
  wprep<<<128, 256, 0, stream>>>(n2c_wl, n2c_wr, c2n_wl, c2n_wr, wp);

  // prologue: frc = xc @ n2c_wr[0] + br[0]
  gemm_mfma_h<<<GB_C, 512, 0, stream>>>(xch, xcl, wp + (size_t)4 * 32768,
                                        n2c_br, frc, NCLS);

  // ---- layers ----
  for (int l = 0; l < NLAY; ++l) {
    // node-side dual launch: flb = xn @ n2c_wl[l]; frn = xn @ c2n_wr[l]
    gemm_mfma_h2<<<2 * GB_N, 512, 0, stream>>>(xnh, xnl,
                                               wp + (size_t)(0 + l) * 32768, n2c_bl + l * HID, flb,
                                               wp + (size_t)(12 + l) * 32768, c2n_br + l * HID, frn,
                                               NNODE, GB_N);
    // n2c gat: dst=class
    gat_dst<<<GAT_BLOCKS, 256, 0, stream>>>(xch, xcl, flb, frc, rowptr_c, csr_c,
                                            n2c_att + l * HID, n2c_bias + l * HID,
                                            ln_cg + l * HID, ln_cb + l * HID, NCLS);
    // class-side: flb = xc @ c2n_wl[l]; frc = xc @ n2c_wr[l+1] (when it exists)
    if (l < NLAY - 1) {
      gemm_mfma_h2<<<2 * GB_C, 512, 0, stream>>>(xch, xcl,
                                                 wp + (size_t)(8 + l) * 32768, c2n_bl + l * HID, flb,
                                                 wp + (size_t)(4 + l + 1) * 32768, n2c_br + (l + 1) * HID, frc,
                                                 NCLS, GB_C);
    } else {
      gemm_mfma_h<<<GB_C, 512, 0, stream>>>(xch, xcl, wp + (size_t)(8 + l) * 32768,
                                            c2n_bl + l * HID, flb, NCLS);
    }
    // c2n gat: dst=node
    gat_dst<<<GAT_BLOCKS, 256, 0, stream>>>(xnh, xnl, flb, frn, rowptr_n, csr_n,
                                            c2n_att + l * HID, c2n_bias + l * HID,
                                            ln_ng + l * HID, ln_nb + l * HID, NNODE);
  }

  hipMemsetAsync(accb, 0, HID * sizeof(float), stream);
  colsum<<<512, 256, 0, stream>>>(xch, xcl, accb);
  final_out<<<1, 128, 0, stream>>>(accb, (float*)d_out);
}

// Round 22
// 884.744 us; speedup vs baseline: 1.1999x; 1.0128x over previous
//
#include <hip/hip_runtime.h>

#define NNODE 100000
#define NCLS  50000
#define NEDGE 400000
#define NDIM  43
#define CDIM  2
#define HID   128
#define NHEAD 4
#define CHN   32
#define NLAY  4

typedef unsigned short u16;
typedef unsigned int u32;
typedef __attribute__((ext_vector_type(8))) short bf16x8;
typedef __attribute__((ext_vector_type(4))) float f32x4;

// fp32 -> bf16 round-to-nearest-even
__device__ __forceinline__ u16 f2bf(float f) {
  u32 u = __float_as_uint(f);
  return (u16)((u + 0x7FFFu + ((u >> 16) & 1u)) >> 16);
}
__device__ __forceinline__ float bf2f(u16 h) {
  return __uint_as_float(((u32)h) << 16);
}

// ---------------------------------------------------------------------------
// Class projection (K=2): writes hi/lo bf16 state arrays.
__global__ void proj_kernel(const float* __restrict__ X, const float* __restrict__ W,
                            const float* __restrict__ B, u16* __restrict__ Yh,
                            u16* __restrict__ Yl, int nrows, int K) {
  int t = blockIdx.x * blockDim.x + threadIdx.x;
  if (t >= nrows * HID) return;
  int i = t >> 7, j = t & (HID - 1);
  float acc = B[j];
  for (int k = 0; k < K; ++k)
    acc = fmaf(X[i * K + k], W[k * HID + j], acc);
  u16 h = f2bf(acc);
  Yh[t] = h;
  Yl[t] = f2bf(acc - bf2f(h));
}

// ---------------------------------------------------------------------------
// Node projection, K=43, LDS-tiled. Writes hi/lo bf16 state arrays.
__global__ __launch_bounds__(256) void proj_node(const float* __restrict__ X,
                                                 const float* __restrict__ W,
                                                 const float* __restrict__ B,
                                                 u16* __restrict__ Yh,
                                                 u16* __restrict__ Yl) {
  __shared__ float Ws[NDIM][HID];   // 22016 B, [k][j]
  __shared__ float Xs[32][NDIM];    // 5504 B,  [r][k]
  const int tid = threadIdx.x;
  const int row0 = blockIdx.x * 32;

  for (int i = tid; i < NDIM * (HID / 4); i += 256) {
    int k = i >> 5, j4 = (i & 31) << 2;
    *(float4*)&Ws[k][j4] = *(const float4*)&W[(size_t)k * HID + j4];
  }
  const float* Xb = X + (size_t)row0 * NDIM;
  for (int i = tid; i < 32 * NDIM; i += 256) ((float*)Xs)[i] = Xb[i];
  __syncthreads();

  const int cg = tid & 31, rg = tid >> 5;
  const int j0 = cg * 4, r0 = rg * 4;

  float acc[4][4];
#pragma unroll
  for (int rr = 0; rr < 4; ++rr)
#pragma unroll
    for (int cc = 0; cc < 4; ++cc) acc[rr][cc] = 0.f;

#pragma unroll 4
  for (int k = 0; k < NDIM; ++k) {
    const float4 w = *(const float4*)&Ws[k][j0];
    const float wv[4] = {w.x, w.y, w.z, w.w};
    const float xx[4] = {Xs[r0 + 0][k], Xs[r0 + 1][k], Xs[r0 + 2][k], Xs[r0 + 3][k]};
#pragma unroll
    for (int rr = 0; rr < 4; ++rr)
#pragma unroll
      for (int cc = 0; cc < 4; ++cc)
        acc[rr][cc] = fmaf(xx[rr], wv[cc], acc[rr][cc]);
  }

  const float4 bv = *(const float4*)&B[j0];
  const float bb[4] = {bv.x, bv.y, bv.z, bv.w};
#pragma unroll
  for (int rr = 0; rr < 4; ++rr) {
    int gr = row0 + r0 + rr;
    ushort4 ho, lo_;
    float v0 = acc[rr][0] + bb[0], v1 = acc[rr][1] + bb[1];
    float v2 = acc[rr][2] + bb[2], v3 = acc[rr][3] + bb[3];
    ho.x = f2bf(v0); lo_.x = f2bf(v0 - bf2f(ho.x));
    ho.y = f2bf(v1); lo_.y = f2bf(v1 - bf2f(ho.y));
    ho.z = f2bf(v2); lo_.z = f2bf(v2 - bf2f(ho.z));
    ho.w = f2bf(v3); lo_.w = f2bf(v3 - bf2f(ho.w));
    *(ushort4*)&Yh[(size_t)gr * HID + j0] = ho;
    *(ushort4*)&Yl[(size_t)gr * HID + j0] = lo_;
  }
}

// ---------------------------------------------------------------------------
// Weight prep: W [128][128] fp32 -> MFMA B-fragment-ordered bf16 hi/lo.
__global__ __launch_bounds__(256) void wprep(const float* __restrict__ n2c_wl,
                                             const float* __restrict__ n2c_wr,
                                             const float* __restrict__ c2n_wl,
                                             const float* __restrict__ c2n_wr,
                                             u16* __restrict__ wp) {
  int gid = blockIdx.x * 256 + threadIdx.x;  // 32768 total
  int lane = gid & 63;
  int t = gid >> 6;                          // 512: m(16) x ks(4) x ct(8)
  int ct = t & 7, ks = (t >> 3) & 3, m = t >> 5;
  const float* Wb;
  switch (m >> 2) {
    case 0: Wb = n2c_wl; break;
    case 1: Wb = n2c_wr; break;
    case 2: Wb = c2n_wl; break;
    default: Wb = c2n_wr; break;
  }
  Wb += (size_t)(m & 3) * HID * HID;
  const int kg = lane >> 4, c = ct * 16 + (lane & 15);
  u16 hi[8], lo[8];
#pragma unroll
  for (int e = 0; e < 8; ++e) {
    float v = Wb[(size_t)(ks * 32 + kg * 8 + e) * HID + c];
    hi[e] = f2bf(v);
    lo[e] = f2bf(v - bf2f(hi[e]));
  }
  size_t base = (size_t)m * 32768 + ((size_t)(ks * 8 + ct) * 64 + lane) * 8;
#pragma unroll
  for (int e = 0; e < 8; ++e) {
    wp[base + e] = hi[e];
    wp[base + 16384 + e] = lo[e];
  }
}

// ---------------------------------------------------------------------------
// MFMA-GEMM v3: 512 threads (8 waves), 128 rows/block, 16 rows/wave.
// The full 64KB packed W (hi+lo) is staged ONCE per block into LDS
// (coalesced 16B/thread), then all B-frag reads are conflict-free
// ds_read_b128 (lane-linear 1KB spans) instead of repeated L2 streams.
#define GEMM_STAGE                                                     \
  _Pragma("unroll") for (int q = 0; q < 8; ++q) {                      \
    int i = (tid + q * 512) * 8;                                       \
    *(bf16x8*)&Wl[i] = *(const bf16x8*)&wp[i];                         \
  }

#define GEMM_FRAME                                                     \
  const int lane = tid & 63;                                           \
  const int wv = tid >> 6;                                             \
  const int row0 = blk * 128 + wv * 16;                                \
  const int ri = lane & 15;                                            \
  const int kg = lane >> 4;                                            \
  int r = row0 + ri;                                                   \
  r = r < nrows ? r : nrows - 1;                                       \
  const size_t xbase = (size_t)r * HID + kg * 8;                       \
  bf16x8 Ah[4], Al[4];                                                 \
  _Pragma("unroll") for (int ks = 0; ks < 4; ++ks) {                   \
    Ah[ks] = *(const bf16x8*)&Xh[xbase + ks * 32];                     \
    Al[ks] = *(const bf16x8*)&Xl[xbase + ks * 32];                     \
  }

#define GEMM_CORE                                                                         \
  f32x4 acc[8];                                                                           \
  _Pragma("unroll") for (int ct = 0; ct < 8; ++ct) acc[ct] = (f32x4){0.f, 0.f, 0.f, 0.f}; \
  _Pragma("unroll") for (int ks = 0; ks < 4; ++ks) {                                      \
    const u16* wb = Wl + ((size_t)(ks * 8) * 64 + lane) * 8;                              \
    _Pragma("unroll") for (int ct = 0; ct < 8; ++ct) {                                    \
      bf16x8 Bh = *(const bf16x8*)&wb[ct * 512];                                          \
      bf16x8 Bl = *(const bf16x8*)&wb[16384 + ct * 512];                                  \
      acc[ct] = __builtin_amdgcn_mfma_f32_16x16x32_bf16(Ah[ks], Bh, acc[ct], 0, 0, 0);    \
      acc[ct] = __builtin_amdgcn_mfma_f32_16x16x32_bf16(Al[ks], Bh, acc[ct], 0, 0, 0);    \
      acc[ct] = __builtin_amdgcn_mfma_f32_16x16x32_bf16(Ah[ks], Bl, acc[ct], 0, 0, 0);    \
    }                                                                                     \
  }

#define GEMM_STORE                                                     \
  _Pragma("unroll") for (int ct = 0; ct < 8; ++ct) {                   \
    const float bias = B[ct * 16 + ri];                                \
    _Pragma("unroll") for (int i = 0; i < 4; ++i) {                    \
      int gr = row0 + kg * 4 + i;                                      \
      if (gr < nrows) Y[(size_t)gr * HID + ct * 16 + ri] =             \
          f2bf(acc[ct][i] + bias);                                     \
    }                                                                  \
  }

// Single GEMM, bf16 output.
__global__ __launch_bounds__(512) void gemm_mfma_h(const u16* __restrict__ Xh,
                                                   const u16* __restrict__ Xl,
                                                   const u16* __restrict__ wp,
                                                   const float* __restrict__ B,
                                                   u16* __restrict__ Y, int nrows) {
  __shared__ u16 Wl[32768];  // 64 KB
  const int tid = threadIdx.x;
  const int blk = blockIdx.x;
  GEMM_STAGE
  GEMM_FRAME
  __syncthreads();
  GEMM_CORE
  GEMM_STORE
}

// Dual-GEMM in one launch via grid partition.
__global__ __launch_bounds__(512) void gemm_mfma_h2(const u16* __restrict__ Xh,
                                                    const u16* __restrict__ Xl,
                                                    const u16* __restrict__ wpA,
                                                    const float* __restrict__ BA,
                                                    u16* __restrict__ YA,
                                                    const u16* __restrict__ wpB,
                                                    const float* __restrict__ BB,
                                                    u16* __restrict__ YB,
                                                    int nrows, int gbase) {
  __shared__ u16 Wl[32768];  // 64 KB
  const int tid = threadIdx.x;
  const bool second = (int)blockIdx.x >= gbase;
  const u16* wp = second ? wpB : wpA;
  const float* B = second ? BB : BA;
  u16* Y = second ? YB : YA;
  const int blk = second ? blockIdx.x - gbase : blockIdx.x;
  GEMM_STAGE
  GEMM_FRAME
  __syncthreads();
  GEMM_CORE
  GEMM_STORE
}

// ---------------------------------------------------------------------------
// CSR build (both graphs per launch): histogram -> scan -> scatter
__global__ void hist2(const int* __restrict__ mdst, const int* __restrict__ cdst,
                      int* __restrict__ cnt_c, int* __restrict__ cnt_n) {
  int e = blockIdx.x * 256 + threadIdx.x;
  if (e < NEDGE) atomicAdd(&cnt_c[mdst[e]], 1);
  else {
    e -= NEDGE;
    if (e < NEDGE) atomicAdd(&cnt_n[cdst[e]], 1);
  }
}

// block bb covers 1024 elements (4/thread); pre[i] = exclusive prefix in block
__global__ __launch_bounds__(256) void scan2(const int* __restrict__ cnt_c,
                                             int* __restrict__ pre_c,
                                             int* __restrict__ bsum_c,
                                             const int* __restrict__ cnt_n,
                                             int* __restrict__ pre_n,
                                             int* __restrict__ bsum_n, int nbC) {
  __shared__ int sdata[256];
  const int b = blockIdx.x, t = threadIdx.x;
  const int* cnt; int* pre; int* bsum; int n; int bb;
  if (b < nbC) { cnt = cnt_c; pre = pre_c; bsum = bsum_c; n = NCLS; bb = b; }
  else { cnt = cnt_n; pre = pre_n; bsum = bsum_n; n = NNODE; bb = b - nbC; }
  const int base = bb * 1024 + t * 4;
  int v[4], s = 0;
#pragma unroll
  for (int q = 0; q < 4; ++q) {
    int i = base + q;
    v[q] = (i < n) ? cnt[i] : 0;
    s += v[q];
  }
  sdata[t] = s;
  __syncthreads();
  for (int off = 1; off < 256; off <<= 1) {
    int y = (t >= off) ? sdata[t - off] : 0;
    __syncthreads();
    sdata[t] += y;
    __syncthreads();
  }
  int run = sdata[t] - s;
  if (t == 255) bsum[bb] = sdata[255];
#pragma unroll
  for (int q = 0; q < 4; ++q) {
    int i = base + q;
    if (i < n) pre[i] = run;
    run += v[q];
  }
}

// 2 blocks: block 0 scans bsum_c (nbC), block 1 bsum_n (nbN); nb <= 128
__global__ __launch_bounds__(128) void scanp2(int* __restrict__ bsum_c, int nbC,
                                              int* __restrict__ bsum_n, int nbN) {
  __shared__ int sd[128];
  int* bs = blockIdx.x ? bsum_n : bsum_c;
  int nb = blockIdx.x ? nbN : nbC;
  int t = threadIdx.x;
  int v = (t < nb) ? bs[t] : 0;
  sd[t] = v;
  __syncthreads();
  for (int off = 1; off < 128; off <<= 1) {
    int y = (t >= off) ? sd[t - off] : 0;
    __syncthreads();
    sd[t] += y;
    __syncthreads();
  }
  if (t < nb) bs[t] = sd[t] - v;  // exclusive
}

__global__ void fin2(const int* __restrict__ pre_c, const int* __restrict__ bsum_c,
                     int* __restrict__ rowptr_c,
                     const int* __restrict__ pre_n, const int* __restrict__ bsum_n,
                     int* __restrict__ rowptr_n) {
  int i = blockIdx.x * 256 + threadIdx.x;
  if (i < NCLS) {
    rowptr_c[i] = pre_c[i] + bsum_c[i >> 10];
    if (i == 0) { rowptr_c[NCLS] = NEDGE; rowptr_n[NNODE] = NEDGE; }
  } else {
    int t = i - NCLS;
    if (t < NNODE) rowptr_n[t] = pre_n[t] + bsum_n[t >> 10];
  }
}

__global__ void scatter2(const int* __restrict__ msrc, const int* __restrict__ mdst,
                         const int* __restrict__ rowptr_c, int* __restrict__ cur_c,
                         int* __restrict__ csr_c,
                         const int* __restrict__ csrc, const int* __restrict__ cdst,
                         const int* __restrict__ rowptr_n, int* __restrict__ cur_n,
                         int* __restrict__ csr_n) {
  int e = blockIdx.x * 256 + threadIdx.x;
  if (e < NEDGE) {
    int d = mdst[e];
    int p = atomicAdd(&cur_c[d], 1);
    csr_c[rowptr_c[d] + p] = msrc[e];
  } else {
    e -= NEDGE;
    if (e < NEDGE) {
      int d = cdst[e];
      int p = atomicAdd(&cur_n[d], 1);
      csr_n[rowptr_n[d] + p] = csrc[e];
    }
  }
}

// ---------------------------------------------------------------------------
// Fused per-dst GATv2: TWO rows per wave, 4-deep edge unroll
// (8 edge-gathers in flight per wave). Lanes 0-31 -> row 2t, 32-63 -> 2t+1;
// 4 channels/lane. Degree mismatch branchless (invalid edges e_=0).
__global__ __launch_bounds__(256) void gat_dst(u16* __restrict__ xh,
                                               u16* __restrict__ xlo,
                                               const u16* __restrict__ flh,    // [n_src][128] bf16
                                               const u16* __restrict__ frh,    // [n_dst][128] bf16
                                               const int* __restrict__ rowptr,
                                               const int* __restrict__ csr_src,
                                               const float* __restrict__ att,  // [128]
                                               const float* __restrict__ bias,
                                               const float* __restrict__ g,
                                               const float* __restrict__ b,
                                               int n_dst) {
  const int wave = threadIdx.x >> 6;     // 0..3
  const int lane = threadIdx.x & 63;
  const int half = lane >> 5;            // row within pair
  const int sub = lane & 31;
  const int j0 = sub * 4;                // channels j0..j0+3; head = sub>>3

  const float4 attv = *(const float4*)&att[j0];
  const float4 bias4 = *(const float4*)&bias[j0];
  const float4 g4 = *(const float4*)&g[j0];
  const float4 b4 = *(const float4*)&b[j0];

  const int npairs = n_dst >> 1;
  const int stride = gridDim.x * 4;
  for (int t = blockIdx.x * 4 + wave; t < npairs; t += stride) {
    const int d = 2 * t + half;
    const ushort4 rr = *(const ushort4*)&frh[(size_t)d * HID + j0];
    const float xr0 = bf2f(rr.x), xr1 = bf2f(rr.y), xr2 = bf2f(rr.z), xr3 = bf2f(rr.w);
    const int e0 = rowptr[d], e1 = rowptr[d + 1];
    const int deg = e1 - e0;
    const int dego = __shfl_xor(deg, 32);
    const int kmax = deg > dego ? deg : dego;

    float a0 = 0.f, a1 = 0.f, a2 = 0.f, a3 = 0.f, den = 0.f;

#define GAT_EDGE(wv, ok)                                              \
    {                                                                 \
      float c0 = bf2f(wv.x), c1 = bf2f(wv.y);                         \
      float c2 = bf2f(wv.z), c3 = bf2f(wv.w);                         \
      float m0 = c0 + xr0; m0 = m0 > 0.f ? m0 : 0.2f * m0;            \
      float m1 = c1 + xr1; m1 = m1 > 0.f ? m1 : 0.2f * m1;            \
      float m2 = c2 + xr2; m2 = m2 > 0.f ? m2 : 0.2f * m2;            \
      float m3 = c3 + xr3; m3 = m3 > 0.f ? m3 : 0.2f * m3;            \
      float p = fmaf(attv.x, m0, fmaf(attv.y, m1,                      \
                fmaf(attv.z, m2, attv.w * m3)));                      \
      p += __shfl_xor(p, 1);                                          \
      p += __shfl_xor(p, 2);                                          \
      p += __shfl_xor(p, 4);                                          \
      float e_ = (ok) ? __expf(p) : 0.f;                              \
      a0 = fmaf(e_, c0, a0); a1 = fmaf(e_, c1, a1);                   \
      a2 = fmaf(e_, c2, a2); a3 = fmaf(e_, c3, a3);                   \
      den += e_;                                                      \
    }

    int k = 0;
    for (; k + 3 < kmax; k += 4) {
      int idx = e0 + k;
      bool ok0 = idx < e1, ok1 = idx + 1 < e1, ok2 = idx + 2 < e1, ok3 = idx + 3 < e1;
      int i0 = min(idx, NEDGE - 1), i1 = min(idx + 1, NEDGE - 1);
      int i2 = min(idx + 2, NEDGE - 1), i3 = min(idx + 3, NEDGE - 1);
      int s0 = csr_src[i0], s1 = csr_src[i1], s2 = csr_src[i2], s3 = csr_src[i3];
      ushort4 w0 = *(const ushort4*)&flh[(size_t)s0 * HID + j0];
      ushort4 w1 = *(const ushort4*)&flh[(size_t)s1 * HID + j0];
      ushort4 w2 = *(const ushort4*)&flh[(size_t)s2 * HID + j0];
      ushort4 w3 = *(const ushort4*)&flh[(size_t)s3 * HID + j0];
      GAT_EDGE(w0, ok0)
      GAT_EDGE(w1, ok1)
      GAT_EDGE(w2, ok2)
      GAT_EDGE(w3, ok3)
    }
    for (; k < kmax; ++k) {
      int idx = e0 + k;
      bool ok0 = idx < e1;
      int i0 = min(idx, NEDGE - 1);
      int s0 = csr_src[i0];
      ushort4 w0 = *(const ushort4*)&flh[(size_t)s0 * HID + j0];
      GAT_EDGE(w0, ok0)
    }
#undef GAT_EDGE

    float rden = (e1 > e0) ? 1.0f / den : 0.f;
    float o0 = a0 * rden, o1 = a1 * rden, o2 = a2 * rden, o3 = a3 * rden;

    // residual from hi/lo state
    const ushort4 hh = *(const ushort4*)&xh[(size_t)d * HID + j0];
    const ushort4 ll = *(const ushort4*)&xlo[(size_t)d * HID + j0];
    float v0 = bf2f(hh.x) + bf2f(ll.x) + o0 + bias4.x;
    float v1 = bf2f(hh.y) + bf2f(ll.y) + o1 + bias4.y;
    float v2 = bf2f(hh.z) + bf2f(ll.z) + o2 + bias4.z;
    float v3 = bf2f(hh.w) + bf2f(ll.w) + o3 + bias4.w;

    // LayerNorm within the 32-lane half (32 lanes x 4 channels = 128)
    float s1 = v0 + v1 + v2 + v3;
    float s2 = v0 * v0 + v1 * v1 + v2 * v2 + v3 * v3;
#pragma unroll
    for (int off = 16; off > 0; off >>= 1) {
      s1 += __shfl_xor(s1, off);
      s2 += __shfl_xor(s2, off);
    }
    const float mu = s1 * (1.0f / HID);
    const float var = s2 * (1.0f / HID) - mu * mu;
    const float inv = rsqrtf(var + 1e-5f);
    float o0n = (v0 - mu) * inv * g4.x + b4.x;
    float o1n = (v1 - mu) * inv * g4.y + b4.y;
    float o2n = (v2 - mu) * inv * g4.z + b4.z;
    float o3n = (v3 - mu) * inv * g4.w + b4.w;

    ushort4 ho, lo_;
    ho.x = f2bf(o0n); lo_.x = f2bf(o0n - bf2f(ho.x));
    ho.y = f2bf(o1n); lo_.y = f2bf(o1n - bf2f(ho.y));
    ho.z = f2bf(o2n); lo_.z = f2bf(o2n - bf2f(ho.z));
    ho.w = f2bf(o3n); lo_.w = f2bf(o3n - bf2f(ho.w));
    *(ushort4*)&xh[(size_t)d * HID + j0] = ho;
    *(ushort4*)&xlo[(size_t)d * HID + j0] = lo_;
  }
}

// ---------------------------------------------------------------------------
// colsum v2: vectorized + latency-hiding. 512 blocks x 256 threads.
__global__ __launch_bounds__(256) void colsum(const u16* __restrict__ xh,
                                              const u16* __restrict__ xlo,
                                              float* __restrict__ acc) {
  const int t = threadIdx.x;
  const int cg = t & 15;
  const int c0 = cg * 8;
  float s[8];
#pragma unroll
  for (int e = 0; e < 8; ++e) s[e] = 0.f;

  const int stride = gridDim.x * 16;
  for (int r = blockIdx.x * 16 + (t >> 4); r < NCLS; r += stride) {
    const u16* ph = &xh[(size_t)r * HID + c0];
    const u16* pl = &xlo[(size_t)r * HID + c0];
    ushort4 h0 = *(const ushort4*)ph;
    ushort4 h1 = *(const ushort4*)(ph + 4);
    ushort4 l0 = *(const ushort4*)pl;
    ushort4 l1 = *(const ushort4*)(pl + 4);
    s[0] += bf2f(h0.x) + bf2f(l0.x);
    s[1] += bf2f(h0.y) + bf2f(l0.y);
    s[2] += bf2f(h0.z) + bf2f(l0.z);
    s[3] += bf2f(h0.w) + bf2f(l0.w);
    s[4] += bf2f(h1.x) + bf2f(l1.x);
    s[5] += bf2f(h1.y) + bf2f(l1.y);
    s[6] += bf2f(h1.z) + bf2f(l1.z);
    s[7] += bf2f(h1.w) + bf2f(l1.w);
  }

  __shared__ float red[256][8];  // 8 KB
#pragma unroll
  for (int e = 0; e < 8; ++e) red[t][e] = s[e];
  __syncthreads();
  if (t < 128) {
    int cg2 = t >> 3, e = t & 7;
    float sum = 0.f;
#pragma unroll
    for (int st = 0; st < 16; ++st) sum += red[st * 16 + cg2][e];
    atomicAdd(&acc[cg2 * 8 + e], sum);
  }
}

__global__ void final_out(const float* __restrict__ acc, float* __restrict__ out) {
  int j = threadIdx.x;
  out[j] = acc[j] * (1.0f / NCLS);
}

// ---------------------------------------------------------------------------
extern "C" void kernel_launch(void* const* d_in, const int* in_sizes, int n_in,
                              void* d_out, int out_size, void* d_ws, size_t ws_size,
                              hipStream_t stream) {
  (void)in_sizes; (void)n_in; (void)out_size; (void)ws_size;
  const float* x_node     = (const float*)d_in[0];
  const float* x_class    = (const float*)d_in[1];
  const int* member_src   = (const int*)d_in[2];
  const int* member_dst   = (const int*)d_in[3];
  const int* contains_src = (const int*)d_in[4];
  const int* contains_dst = (const int*)d_in[5];
  const float* npw = (const float*)d_in[6];
  const float* npb = (const float*)d_in[7];
  const float* cpw = (const float*)d_in[8];
  const float* cpb = (const float*)d_in[9];
  const float* n2c_wl   = (const float*)d_in[10];
  const float* n2c_bl   = (const float*)d_in[11];
  const float* n2c_wr   = (const float*)d_in[12];
  const float* n2c_br   = (const float*)d_in[13];
  const float* n2c_att  = (const float*)d_in[14];
  const float* n2c_bias = (const float*)d_in[15];
  const float* c2n_wl   = (const float*)d_in[16];
  const float* c2n_bl   = (const float*)d_in[17];
  const float* c2n_wr   = (const float*)d_in[18];
  const float* c2n_br   = (const float*)d_in[19];
  const float* c2n_att  = (const float*)d_in[20];
  const float* c2n_bias = (const float*)d_in[21];
  const float* ln_cg = (const float*)d_in[22];
  const float* ln_cb = (const float*)d_in[23];
  const float* ln_ng = (const float*)d_in[24];
  const float* ln_nb = (const float*)d_in[25];

  // workspace layout
  u16* xnh = (u16*)d_ws;                             // NNODE*128 u16
  u16* xnl = xnh + (size_t)NNODE * HID;              // NNODE*128
  u16* xch = xnl + (size_t)NNODE * HID;              // NCLS*128
  u16* xcl = xch + (size_t)NCLS * HID;               // NCLS*128
  u16* flb = xcl + (size_t)NCLS * HID;               // NNODE*128 bf16
  u16* frn = flb + (size_t)NNODE * HID;              // NNODE*128 bf16
  u16* frc = frn + (size_t)NNODE * HID;              // NCLS*128 bf16
  float* accb = (float*)(frc + (size_t)NCLS * HID);  // 128
  int* rowptr_c = (int*)(accb + 128);                // NCLS+1
  int* csr_c    = rowptr_c + (NCLS + 1);             // NEDGE
  int* rowptr_n = csr_c + NEDGE;                     // NNODE+1
  int* csr_n    = rowptr_n + (NNODE + 1);            // NEDGE
  int* cnt_c    = csr_n + NEDGE;                     // NCLS (cnt_c..cur_n contiguous, 1 memset)
  int* cur_c    = cnt_c + NCLS;                      // NCLS
  int* cnt_n    = cur_c + NCLS;                      // NNODE
  int* cur_n    = cnt_n + NNODE;                     // NNODE
  int* pre_c    = cur_n + NNODE;                     // NCLS
  int* pre_n    = pre_c + NCLS;                      // NNODE
  int* bsum_c   = pre_n + NNODE;                     // 128
  int* bsum_n   = bsum_c + 128;                      // 128
  // packed weights overlay cnt/cursor region after CSR build (1 MB <= 1.2 MB)
  u16* wp = (u16*)cnt_c;

  const int nbC = (NCLS + 1023) / 1024;   // 49
  const int nbN = (NNODE + 1023) / 1024;  // 98
  const int EB2 = (2 * NEDGE + 255) / 256;
  const int GAT_BLOCKS = 8192;  // 4x oversubscribed persistent grid: tail balance
  const int GB_N = (NNODE + 127) / 128;   // 128 rows/block (512 threads)
  const int GB_C = (NCLS + 127) / 128;

  // ---- initial projections (write hi/lo state) ----
  proj_node<<<NNODE / 32, 256, 0, stream>>>(x_node, npw, npb, xnh, xnl);
  proj_kernel<<<(NCLS * HID + 255) / 256, 256, 0, stream>>>(x_class, cpw, cpb, xch, xcl, NCLS, CDIM);

  // ---- CSR build (both graphs per launch) ----
  hipMemsetAsync(cnt_c, 0, (size_t)(2 * NCLS + 2 * NNODE) * sizeof(int), stream);
  hist2<<<EB2, 256, 0, stream>>>(member_dst, contains_dst, cnt_c, cnt_n);
  scan2<<<nbC + nbN, 256, 0, stream>>>(cnt_c, pre_c, bsum_c, cnt_n, pre_n, bsum_n, nbC);
  scanp2<<<2, 128, 0, stream>>>(bsum_c, nbC, bsum_n, nbN);
  fin2<<<(NCLS + NNODE + 255) / 256, 256, 0, stream>>>(pre_c, bsum_c, rowptr_c,
                                                       pre_n, bsum_n, rowptr_n);
  scatter2<<<EB2, 256, 0, stream>>>(member_src, member_dst, rowptr_c, cur_c, csr_c,
                                    contains_src, contains_dst, rowptr_n, cur_n, csr_n);

  // ---- pack weights (cnt/cursor region dead now) ----
  wprep<<<128, 256, 0, stream>>>(n2c_wl, n2c_wr, c2n_wl, c2n_wr, wp);

  // prologue: frc = xc @ n2c_wr[0] + br[0]
  gemm_mfma_h<<<GB_C, 512, 0, stream>>>(xch, xcl, wp + (size_t)4 * 32768,
                                        n2c_br, frc, NCLS);

  // ---- layers ----
  for (int l = 0; l < NLAY; ++l) {
    // node-side dual launch: flb = xn @ n2c_wl[l]; frn = xn @ c2n_wr[l]
    gemm_mfma_h2<<<2 * GB_N, 512, 0, stream>>>(xnh, xnl,
                                               wp + (size_t)(0 + l) * 32768, n2c_bl + l * HID, flb,
                                               wp + (size_t)(12 + l) * 32768, c2n_br + l * HID, frn,
                                               NNODE, GB_N);
    // n2c gat: dst=class
    gat_dst<<<GAT_BLOCKS, 256, 0, stream>>>(xch, xcl, flb, frc, rowptr_c, csr_c,
                                            n2c_att + l * HID, n2c_bias + l * HID,
                                            ln_cg + l * HID, ln_cb + l * HID, NCLS);
    // class-side: flb = xc @ c2n_wl[l]; frc = xc @ n2c_wr[l+1] (when it exists)
    if (l < NLAY - 1) {
      gemm_mfma_h2<<<2 * GB_C, 512, 0, stream>>>(xch, xcl,
                                                 wp + (size_t)(8 + l) * 32768, c2n_bl + l * HID, flb,
                                                 wp + (size_t)(4 + l + 1) * 32768, n2c_br + (l + 1) * HID, frc,
                                                 NCLS, GB_C);
    } else {
      gemm_mfma_h<<<GB_C, 512, 0, stream>>>(xch, xcl, wp + (size_t)(8 + l) * 32768,
                                            c2n_bl + l * HID, flb, NCLS);
    }
    // c2n gat: dst=node
    gat_dst<<<GAT_BLOCKS, 256, 0, stream>>>(xnh, xnl, flb, frn, rowptr_n, csr_n,
                                            c2n_att + l * HID, c2n_bias + l * HID,
                                            ln_ng + l * HID, ln_nb + l * HID, NNODE);
  }

  hipMemsetAsync(accb, 0, HID * sizeof(float), stream);
  colsum<<<512, 256, 0, stream>>>(xch, xcl, accb);
  final_out<<<1, 128, 0, stream>>>(accb, (float*)d_out);
}